// Round 11
// baseline (10472.003 us; speedup 1.0000x reference)
//
#include <hip/hip_runtime.h>
#include <cstdint>

typedef unsigned long long u64;
typedef unsigned int u32;
typedef float f32x2 __attribute__((ext_vector_type(2)));

#define L_X 16000
#define NB  64
#define P1  5320   // conv1(15960) pool3
#define P2  1746   // conv2(5240) pool3
#define P3  555    // conv3(1666) pool3
#define P4  158    // conv4(475) pool3
#define C5  78     // conv5 out, no pool

// ---- exact scalar chain: A = fl(A + (bit ? -0.1f : +0.1f)), LSB-first (normal pack) ----
__device__ __forceinline__ void chain64(float& A, u64 u) {
    u32 w = (u32)u;
    #pragma unroll
    for (int j = 0; j < 32; ++j)
        A = __fadd_rn(A, __uint_as_float(0x3DCCCCCDu | ((w << (31 - j)) & 0x80000000u)));
    w = (u32)(u >> 32);
    #pragma unroll
    for (int j = 0; j < 32; ++j)
        A = __fadd_rn(A, __uint_as_float(0x3DCCCCCDu | ((w << (31 - j)) & 0x80000000u)));
}

// ---- packed self-shift phase: 32 channels for POOLK independent q-pairs ----
// V[r] = [hi32: q1-chain bits, lo32: q0-chain bits], channel at bit31/bit63, V<<=1 per step.
// Per-half float sequence identical to the scalar chain (per-component RNE adds).
template <int POOLK>
__device__ __forceinline__ void pkphase(f32x2* A, u64* V, u64 base64) {
    #pragma unroll
    for (int j = 0; j < 32; ++j) {
        #pragma unroll
        for (int r = 0; r < POOLK; ++r) {
            u64 t = (V[r] & 0x8000000080000000ull) | base64;
            A[r] = A[r] + __builtin_bit_cast(f32x2, t);
            V[r] <<= 1;
        }
    }
}

// ---------------- packing kernels ----------------
__global__ void pack_w1T(const float* __restrict__ w1, float* __restrict__ w1T) {
    int t = blockIdx.x * blockDim.x + threadIdx.x;
    if (t >= 3 * 41 * 64) return;
    int co = t & 63;
    int rem = t >> 6;
    int k = rem % 41;
    int ci = rem / 41;
    w1T[t] = (w1[((size_t)co * 3 + ci) * 41 + k] < 0.f) ? -0.1f : 0.1f;
}

// conv weights, REVERSED bit order: bit (63-c) = sign of channel h*64+c
__global__ void pack_wT(const float* __restrict__ w, u64* __restrict__ wT,
                        int Co, int CIW) {
    int t = blockIdx.x * blockDim.x + threadIdx.x;
    if (t >= Co * 41 * CIW) return;
    int co = t % Co;
    int rem = t / Co;
    int h = rem % CIW;
    int k = rem / CIW;
    int CI = CIW * 64;
    u64 word = 0;
    for (int c = 0; c < 64; ++c)
        if (w[((size_t)co * CI + h * 64 + c) * 41 + k] < 0.f) word |= 1ull << (63 - c);
    wT[t] = word;
}

// fc weights: NORMAL bit order (consumed by LSB-first chain64)
__global__ void pack_fw1T(const float* __restrict__ w, u64* __restrict__ wT) {
    int t = blockIdx.x * blockDim.x + threadIdx.x;
    if (t >= 156 * 1024) return;
    int row = t & 1023;
    int j = t >> 10;
    const float* base = w + (size_t)row * 9984 + j * 64;
    u64 word = 0;
    for (int c = 0; c < 64; ++c)
        if (base[c] < 0.f) word |= 1ull << c;
    wT[t] = word;
}

__global__ void pack_fw2T(const float* __restrict__ w, u64* __restrict__ wT) {
    int t = blockIdx.x * blockDim.x + threadIdx.x;
    if (t >= 16 * 1000) return;
    int row = t % 1000;
    int j = t / 1000;
    const float* base = w + (size_t)row * 1024 + j * 64;
    u64 word = 0;
    for (int c = 0; c < 64; ++c)
        if (base[c] < 0.f) word |= 1ull << c;
    wT[t] = word;
}

// a5 words are REVERSED (channel chan at bit 63-(chan&63)); a5F is NORMAL order
__global__ void repack_a5(const u64* __restrict__ a5, u64* __restrict__ a5F) {
    int t = blockIdx.x * blockDim.x + threadIdx.x;
    if (t >= NB * 156) return;
    int j = t % 156;
    int n = t / 156;
    u64 word = 0;
    #pragma unroll
    for (int c = 0; c < 64; ++c) {
        int jj = j * 64 + c;
        int chan = jj / 78;
        int tp = jj - chan * 78;
        u64 src = a5[((size_t)n * C5 + tp) * 2 + (chan >> 6)];
        word |= ((src >> (63 - (chan & 63))) & 1ull) << c;
    }
    a5F[t] = word;
}

// ---------------- conv1 + scale_bias + sign + pool3 (reversed output words) ----------------
__global__ __launch_bounds__(64) void conv1_k(
        const float* __restrict__ x, const float* __restrict__ w1T,
        const float* __restrict__ s0, const float* __restrict__ b0,
        const float* __restrict__ s1, const float* __restrict__ b1,
        u64* __restrict__ a1) {
    int q = blockIdx.x;
    int n = blockIdx.y;
    int co = threadIdx.x;
    float sq0[3], bb0[3];
    #pragma unroll
    for (int ci = 0; ci < 3; ++ci) {
        sq0[ci] = (s0[ci] < 0.f) ? -0.1f : 0.1f;
        bb0[ci] = b0[ci];
    }
    float sq1 = (s1[co] < 0.f) ? -0.1f : 0.1f;
    float bb1 = b1[co];
    bool neg = true;
    for (int r = 0; r < 3; ++r) {
        int p = 3 * q + r;
        float S = 0.f;
        #pragma unroll 1
        for (int k = 0; k < 41; ++k) {
            float A = 0.f;
            #pragma unroll
            for (int ci = 0; ci < 3; ++ci) {
                float xv  = x[((size_t)n * 3 + ci) * L_X + p + k];
                float xsb = __fadd_rn(__fmul_rn(xv, sq0[ci]), bb0[ci]);
                float wf  = w1T[(ci * 41 + k) * 64 + co];
                A = __fadd_rn(A, __fmul_rn(xsb, wf));
            }
            S = __fadd_rn(S, A);
        }
        float pre = __fadd_rn(__fmul_rn(S, sq1), bb1);
        neg = neg && (pre < 0.f);
    }
    u64 word = __brevll(__ballot(neg));   // channel co -> bit 63-co
    if (co == 0) a1[(size_t)n * P1 + q] = word;
}

// ---------------- binary conv: 2 q-positions/thread, self-shift pk chains ----------------
// block = Co threads; grid ((Lq+1)/2, NB). abits_in: [(n*Lin + pos)*CIW + h], REVERSED words
template <int CIW, int POOLK>
__global__ void bconv_pk(const u64* __restrict__ abits_in, const u64* __restrict__ wT,
                         const float* __restrict__ s, const float* __restrict__ b,
                         u64* __restrict__ abits_out, int Lin, int Lq, u64 base64) {
    int q2 = blockIdx.x;
    int n  = blockIdx.y;
    int co = threadIdx.x;
    int Co = blockDim.x;
    int wave = co >> 6;
    int CoW = Co >> 6;
    int q0 = 2 * q2;
    int q1 = min(q0 + 1, Lq - 1);          // clamp phantom (odd Lq): duplicate compute
    int doff = (q1 - q0) * POOLK;          // POOLK or 0

    float sqf = (s[co] < 0.f) ? -0.1f : 0.1f;
    float bf  = b[co];

    const u64* wp = wT + co;
    const u64* ap = abits_in + ((size_t)n * Lin + (size_t)POOLK * q0) * CIW;

    f32x2 S[POOLK];
    #pragma unroll
    for (int r = 0; r < POOLK; ++r) S[r] = (f32x2)(0.f, 0.f);

    #pragma unroll 1
    for (int k = 0; k < 41; ++k) {
        u64 wk[CIW];
        #pragma unroll
        for (int h = 0; h < CIW; ++h) wk[h] = wp[((size_t)k * CIW + h) * Co];
        const u64* ak = ap + (size_t)(2 * k) * CIW;

        f32x2 A[POOLK];
        #pragma unroll
        for (int r = 0; r < POOLK; ++r) A[r] = (f32x2)(0.f, 0.f);

        #pragma unroll
        for (int h = 0; h < CIW; ++h) {
            u64 uA[POOLK], uB[POOLK], V[POOLK];
            #pragma unroll
            for (int r = 0; r < POOLK; ++r) {
                uA[r] = ak[r * CIW + h] ^ wk[h];           // q0 chain bits
                uB[r] = ak[(doff + r) * CIW + h] ^ wk[h];  // q1 chain bits
            }
            // channels h*64 + 0..31 live in the HIGH halves (reversed pack)
            #pragma unroll
            for (int r = 0; r < POOLK; ++r)
                V[r] = (uA[r] >> 32) | (uB[r] & 0xFFFFFFFF00000000ull);
            pkphase<POOLK>(A, V, base64);
            // channels h*64 + 32..63 live in the LOW halves
            #pragma unroll
            for (int r = 0; r < POOLK; ++r)
                V[r] = (u64)(u32)uA[r] | (uB[r] << 32);
            pkphase<POOLK>(A, V, base64);
        }
        #pragma unroll
        for (int r = 0; r < POOLK; ++r) S[r] = S[r] + A[r];  // per-half fl add
    }

    bool neg0 = true, neg1 = true;
    #pragma unroll
    for (int r = 0; r < POOLK; ++r) {
        neg0 = neg0 && (__fadd_rn(__fmul_rn(S[r].x, sqf), bf) < 0.f);
        neg1 = neg1 && (__fadd_rn(__fmul_rn(S[r].y, sqf), bf) < 0.f);
    }
    u64 word0 = __brevll(__ballot(neg0));
    u64 word1 = __brevll(__ballot(neg1));
    if ((co & 63) == 0) {
        abits_out[((size_t)n * Lq + q0) * CoW + wave] = word0;
        abits_out[((size_t)n * Lq + q1) * CoW + wave] = word1;
    }
}

// ---------------- fc1: single sequential chain over 9984 bits (normal pack) ----------------
__global__ __launch_bounds__(64) void fc1_k(
        const u64* __restrict__ a5F, const u64* __restrict__ fw1T,
        const float* __restrict__ s6, const float* __restrict__ b6,
        u64* __restrict__ y6b) {
    int g = blockIdx.x;
    int n = blockIdx.y;
    int lane = threadIdx.x;
    int row = g * 64 + lane;
    float S = 0.f;
    #pragma unroll 1
    for (int j = 0; j < 156; ++j) {
        u64 u = a5F[(size_t)n * 156 + j] ^ fw1T[(size_t)j * 1024 + row];
        chain64(S, u);
    }
    float pre = __fadd_rn(__fmul_rn(S, (s6[row] < 0.f) ? -0.1f : 0.1f), b6[row]);
    u64 word = __ballot(pre < 0.f);
    if (lane == 0) y6b[n * 16 + g] = word;
}

// ---------------- fc2: single chain over 1024 bits -> f32 out ----------------
__global__ void fc2_k(const u64* __restrict__ y6b, const u64* __restrict__ fw2T,
                      const float* __restrict__ s7, const float* __restrict__ b7,
                      float* __restrict__ out) {
    int t = blockIdx.x * blockDim.x + threadIdx.x;
    if (t >= NB * 1000) return;
    int r = t % 1000;
    int n = t / 1000;
    float S = 0.f;
    #pragma unroll 1
    for (int j = 0; j < 16; ++j) {
        u64 u = y6b[n * 16 + j] ^ fw2T[j * 1000 + r];
        chain64(S, u);
    }
    out[t] = __fadd_rn(__fmul_rn(S, (s7[r] < 0.f) ? -0.1f : 0.1f), b7[r]);
}

// ---------------- launch ----------------
extern "C" void kernel_launch(void* const* d_in, const int* in_sizes, int n_in,
                              void* d_out, int out_size, void* d_ws, size_t ws_size,
                              hipStream_t stream) {
    const float* x   = (const float*)d_in[0];
    const float* s0  = (const float*)d_in[1];
    const float* b0  = (const float*)d_in[2];
    const float* w1  = (const float*)d_in[3];
    const float* s1  = (const float*)d_in[4];
    const float* b1  = (const float*)d_in[5];
    const float* w2  = (const float*)d_in[6];
    const float* s2  = (const float*)d_in[7];
    const float* b2  = (const float*)d_in[8];
    const float* w3  = (const float*)d_in[9];
    const float* s3  = (const float*)d_in[10];
    const float* b3  = (const float*)d_in[11];
    const float* w4  = (const float*)d_in[12];
    const float* s4  = (const float*)d_in[13];
    const float* b4  = (const float*)d_in[14];
    const float* w5  = (const float*)d_in[15];
    const float* s5  = (const float*)d_in[16];
    const float* b5  = (const float*)d_in[17];
    const float* fw1 = (const float*)d_in[18];
    const float* s6  = (const float*)d_in[19];
    const float* b6  = (const float*)d_in[20];
    const float* fw2 = (const float*)d_in[21];
    const float* s7  = (const float*)d_in[22];
    const float* b7  = (const float*)d_in[23];

    u64* p = (u64*)d_ws;
    float* w1T = (float*)p; p += 3936;
    u64* w2T  = p; p += 41 * 64;
    u64* w3T  = p; p += 41 * 128;
    u64* w4T  = p; p += 82 * 128;
    u64* w5T  = p; p += 82 * 128;
    u64* fw1T = p; p += 156 * 1024;
    u64* fw2T = p; p += 16 * 1000;
    u64* a1   = p; p += (size_t)NB * P1;
    u64* a2   = p; p += (size_t)NB * P2;
    u64* a3   = p; p += (size_t)NB * P3 * 2;
    u64* a4   = p; p += (size_t)NB * P4 * 2;
    u64* a5   = p; p += (size_t)NB * C5 * 2;
    u64* a5F  = p; p += (size_t)NB * 156;
    u64* y6b  = p; p += (size_t)NB * 16;

    const u64 base64 = 0x3DCCCCCD3DCCCCCDull;   // runtime arg -> SGPR pair

    pack_w1T<<<(3 * 41 * 64 + 255) / 256, 256, 0, stream>>>(w1, w1T);
    pack_wT<<<(64 * 41 + 255) / 256, 256, 0, stream>>>(w2, w2T, 64, 1);
    pack_wT<<<(128 * 41 + 255) / 256, 256, 0, stream>>>(w3, w3T, 128, 1);
    pack_wT<<<(128 * 82 + 255) / 256, 256, 0, stream>>>(w4, w4T, 128, 2);
    pack_wT<<<(128 * 82 + 255) / 256, 256, 0, stream>>>(w5, w5T, 128, 2);
    pack_fw1T<<<(156 * 1024 + 255) / 256, 256, 0, stream>>>(fw1, fw1T);
    pack_fw2T<<<(16 * 1000 + 255) / 256, 256, 0, stream>>>(fw2, fw2T);

    conv1_k<<<dim3(P1, NB), 64, 0, stream>>>(x, w1T, s0, b0, s1, b1, a1);
    bconv_pk<1, 3><<<dim3((P2 + 1) / 2, NB), 64, 0, stream>>>(a1, w2T, s2, b2, a2, P1, P2, base64);
    bconv_pk<1, 3><<<dim3((P3 + 1) / 2, NB), 128, 0, stream>>>(a2, w3T, s3, b3, a3, P2, P3, base64);
    bconv_pk<2, 3><<<dim3((P4 + 1) / 2, NB), 128, 0, stream>>>(a3, w4T, s4, b4, a4, P3, P4, base64);
    bconv_pk<2, 1><<<dim3((C5 + 1) / 2, NB), 128, 0, stream>>>(a4, w5T, s5, b5, a5, P4, C5, base64);
    repack_a5<<<(NB * 156 + 255) / 256, 256, 0, stream>>>(a5, a5F);
    fc1_k<<<dim3(16, NB), 64, 0, stream>>>(a5F, fw1T, s6, b6, y6b);
    fc2_k<<<(NB * 1000 + 255) / 256, 256, 0, stream>>>(y6b, fw2T, s7, b7, (float*)d_out);
}

// Round 12
// 7972.282 us; speedup vs baseline: 1.3136x; 1.3136x over previous
//
#include <hip/hip_runtime.h>
#include <cstdint>

typedef unsigned long long u64;
typedef unsigned int u32;

#define L_X 16000
#define NB  64
#define P1  5320   // conv1(15960) pool3
#define P2  1746   // conv2(5240) pool3
#define P3  555    // conv3(1666) pool3
#define P4  158    // conv4(475) pool3
#define C5  78     // conv5 out, no pool

// ---- exact scalar chain: A = fl(A + (bit ? -0.1f : +0.1f)), LSB-first ----
__device__ __forceinline__ void chain64(float& A, u64 u) {
    u32 w = (u32)u;
    #pragma unroll
    for (int j = 0; j < 32; ++j)
        A = __fadd_rn(A, __uint_as_float(0x3DCCCCCDu | ((w << (31 - j)) & 0x80000000u)));
    w = (u32)(u >> 32);
    #pragma unroll
    for (int j = 0; j < 32; ++j)
        A = __fadd_rn(A, __uint_as_float(0x3DCCCCCDu | ((w << (31 - j)) & 0x80000000u)));
}

// ---- table builder: F[t][m] = fl-sum of t terms +-0.1f with count m, if path-independent ----
// verifies fl(F[t-1][m-1]+0.1f) == fl(F[t-1][m+1]-0.1f) at every interior node.
// T64[pc] = F[64][64-2pc], T128[pc] = F[128][128-2pc]. okflag=1 iff property holds (t<=128).
__global__ void build_tab(float* __restrict__ T64, float* __restrict__ T128,
                          int* __restrict__ okflag) {
    __shared__ float buf[2][257];
    __shared__ int ok;
    int tid = threadIdx.x;                 // 256 threads
    if (tid == 0) ok = 1;
    for (int i = tid; i < 257; i += 256) { buf[0][i] = 0.f; buf[1][i] = 0.f; }
    __syncthreads();
    int cur = 0;
    for (int t = 1; t <= 128; ++t) {
        int nx = cur ^ 1;
        for (int i = tid; i < 257; i += 256) {
            int m = i - 128;
            if (((m ^ t) & 1) == 0 && m >= -t && m <= t) {
                float v;
                if (m == t)       v = __fadd_rn(buf[cur][i - 1], 0.1f);
                else if (m == -t) v = __fadd_rn(buf[cur][i + 1], -0.1f);
                else {
                    float vp = __fadd_rn(buf[cur][i - 1], 0.1f);
                    float vm = __fadd_rn(buf[cur][i + 1], -0.1f);
                    if (__float_as_uint(vp) != __float_as_uint(vm)) ok = 0;
                    v = vp;
                }
                buf[nx][i] = v;
            }
        }
        __syncthreads();
        cur = nx;
        if (t == 64) {
            for (int pc = tid; pc <= 64; pc += 256)
                T64[pc] = buf[cur][192 - 2 * pc];
            __syncthreads();
        }
    }
    for (int pc = tid; pc <= 128; pc += 256)
        T128[pc] = buf[cur][256 - 2 * pc];
    __syncthreads();
    if (tid == 0) *okflag = ok;
}

// ---------------- packing kernels (R7 versions, normal LSB-first bit order) ----------------
__global__ void pack_w1T(const float* __restrict__ w1, float* __restrict__ w1T) {
    int t = blockIdx.x * blockDim.x + threadIdx.x;
    if (t >= 3 * 41 * 64) return;
    int co = t & 63;
    int rem = t >> 6;
    int k = rem % 41;
    int ci = rem / 41;
    w1T[t] = (w1[((size_t)co * 3 + ci) * 41 + k] < 0.f) ? -0.1f : 0.1f;
}

__global__ void pack_wT(const float* __restrict__ w, u64* __restrict__ wT,
                        int Co, int CIW) {
    int t = blockIdx.x * blockDim.x + threadIdx.x;
    if (t >= Co * 41 * CIW) return;
    int co = t % Co;
    int rem = t / Co;
    int h = rem % CIW;
    int k = rem / CIW;
    int CI = CIW * 64;
    u64 word = 0;
    for (int c = 0; c < 64; ++c)
        if (w[((size_t)co * CI + h * 64 + c) * 41 + k] < 0.f) word |= 1ull << c;
    wT[t] = word;
}

__global__ void pack_fw1T(const float* __restrict__ w, u64* __restrict__ wT) {
    int t = blockIdx.x * blockDim.x + threadIdx.x;
    if (t >= 156 * 1024) return;
    int row = t & 1023;
    int j = t >> 10;
    const float* base = w + (size_t)row * 9984 + j * 64;
    u64 word = 0;
    for (int c = 0; c < 64; ++c)
        if (base[c] < 0.f) word |= 1ull << c;
    wT[t] = word;
}

__global__ void pack_fw2T(const float* __restrict__ w, u64* __restrict__ wT) {
    int t = blockIdx.x * blockDim.x + threadIdx.x;
    if (t >= 16 * 1000) return;
    int row = t % 1000;
    int j = t / 1000;
    const float* base = w + (size_t)row * 1024 + j * 64;
    u64 word = 0;
    for (int c = 0; c < 64; ++c)
        if (base[c] < 0.f) word |= 1ull << c;
    wT[t] = word;
}

__global__ void repack_a5(const u64* __restrict__ a5, u64* __restrict__ a5F) {
    int t = blockIdx.x * blockDim.x + threadIdx.x;
    if (t >= NB * 156) return;
    int j = t % 156;
    int n = t / 156;
    u64 word = 0;
    #pragma unroll
    for (int c = 0; c < 64; ++c) {
        int jj = j * 64 + c;
        int chan = jj / 78;
        int tp = jj - chan * 78;
        u64 src = a5[((size_t)n * C5 + tp) * 2 + (chan >> 6)];
        word |= ((src >> (chan & 63)) & 1ull) << c;
    }
    a5F[t] = word;
}

// ---------------- conv1 + scale_bias + sign + pool3 (R7) ----------------
__global__ __launch_bounds__(64) void conv1_k(
        const float* __restrict__ x, const float* __restrict__ w1T,
        const float* __restrict__ s0, const float* __restrict__ b0,
        const float* __restrict__ s1, const float* __restrict__ b1,
        u64* __restrict__ a1) {
    int q = blockIdx.x;
    int n = blockIdx.y;
    int co = threadIdx.x;
    float sq0[3], bb0[3];
    #pragma unroll
    for (int ci = 0; ci < 3; ++ci) {
        sq0[ci] = (s0[ci] < 0.f) ? -0.1f : 0.1f;
        bb0[ci] = b0[ci];
    }
    float sq1 = (s1[co] < 0.f) ? -0.1f : 0.1f;
    float bb1 = b1[co];
    bool neg = true;
    for (int r = 0; r < 3; ++r) {
        int p = 3 * q + r;
        float S = 0.f;
        #pragma unroll 1
        for (int k = 0; k < 41; ++k) {
            float A = 0.f;
            #pragma unroll
            for (int ci = 0; ci < 3; ++ci) {
                float xv  = x[((size_t)n * 3 + ci) * L_X + p + k];
                float xsb = __fadd_rn(__fmul_rn(xv, sq0[ci]), bb0[ci]);
                float wf  = w1T[(ci * 41 + k) * 64 + co];
                A = __fadd_rn(A, __fmul_rn(xsb, wf));
            }
            S = __fadd_rn(S, A);
        }
        float pre = __fadd_rn(__fmul_rn(S, sq1), bb1);
        neg = neg && (pre < 0.f);
    }
    u64 word = __ballot(neg);
    if (co == 0) a1[(size_t)n * P1 + q] = word;
}

// ---------------- binary conv: popcount + table (fast) / chain64 (fallback) ----------------
// block = Co threads; grid (Lq, NB). abits_in: [(n*Lin + pos)*CIW + h]
template <int CIW, int POOLK>
__global__ void bconv_tab(const u64* __restrict__ abits_in, const u64* __restrict__ wT,
                          const float* __restrict__ Ttab, const int* __restrict__ okflag,
                          const float* __restrict__ s, const float* __restrict__ b,
                          u64* __restrict__ abits_out, int Lin, int Lq) {
    constexpr int CI = CIW * 64;
    __shared__ float T[CI + 1];
    int q = blockIdx.x;
    int n = blockIdx.y;
    int co = threadIdx.x;
    int Co = blockDim.x;
    int wave = co >> 6;
    int CoW = Co >> 6;
    for (int i = threadIdx.x; i <= CI; i += blockDim.x) T[i] = Ttab[i];
    __syncthreads();
    int ok = *okflag;   // uniform across grid
    float sqf = (s[co] < 0.f) ? -0.1f : 0.1f;
    float bf  = b[co];
    const u64* wp = wT + co;
    const u64* ap = abits_in + ((size_t)n * Lin + (size_t)POOLK * q) * CIW;
    bool neg = true;
    if (ok) {
        // fast path: A_k = T[popcount], S = exact sequential k-sum
        float S[POOLK];
        #pragma unroll
        for (int r = 0; r < POOLK; ++r) S[r] = 0.f;
        #pragma unroll 1
        for (int k = 0; k < 41; ++k) {
            u64 wk[CIW];
            #pragma unroll
            for (int h = 0; h < CIW; ++h) wk[h] = wp[((size_t)k * CIW + h) * Co];
            const u64* ak = ap + (size_t)(2 * k) * CIW;
            #pragma unroll
            for (int r = 0; r < POOLK; ++r) {
                int pc = 0;
                #pragma unroll
                for (int h = 0; h < CIW; ++h)
                    pc += (int)__popcll(ak[r * CIW + h] ^ wk[h]);
                S[r] = __fadd_rn(S[r], T[pc]);
            }
        }
        #pragma unroll
        for (int r = 0; r < POOLK; ++r)
            neg = neg && (__fadd_rn(__fmul_rn(S[r], sqf), bf) < 0.f);
    } else {
        // fallback: R7 exact bit chain
        for (int r = 0; r < POOLK; ++r) {
            float S = 0.f;
            #pragma unroll 1
            for (int k = 0; k < 41; ++k) {
                float A = 0.f;
                #pragma unroll
                for (int h = 0; h < CIW; ++h) {
                    u64 u = ap[(size_t)(2 * k + r) * CIW + h]
                          ^ wp[((size_t)k * CIW + h) * Co];
                    chain64(A, u);
                }
                S = __fadd_rn(S, A);
            }
            neg = neg && (__fadd_rn(__fmul_rn(S, sqf), bf) < 0.f);
        }
    }
    u64 word = __ballot(neg);
    if ((co & 63) == 0) abits_out[((size_t)n * Lq + q) * CoW + wave] = word;
}

// ---------------- fc1: single sequential chain over 9984 bits ----------------
__global__ __launch_bounds__(64) void fc1_k(
        const u64* __restrict__ a5F, const u64* __restrict__ fw1T,
        const float* __restrict__ s6, const float* __restrict__ b6,
        u64* __restrict__ y6b) {
    int g = blockIdx.x;
    int n = blockIdx.y;
    int lane = threadIdx.x;
    int row = g * 64 + lane;
    float S = 0.f;
    #pragma unroll 1
    for (int j = 0; j < 156; ++j) {
        u64 u = a5F[(size_t)n * 156 + j] ^ fw1T[(size_t)j * 1024 + row];
        chain64(S, u);
    }
    float pre = __fadd_rn(__fmul_rn(S, (s6[row] < 0.f) ? -0.1f : 0.1f), b6[row]);
    u64 word = __ballot(pre < 0.f);
    if (lane == 0) y6b[n * 16 + g] = word;
}

// ---------------- fc2: single chain over 1024 bits -> f32 out ----------------
__global__ void fc2_k(const u64* __restrict__ y6b, const u64* __restrict__ fw2T,
                      const float* __restrict__ s7, const float* __restrict__ b7,
                      float* __restrict__ out) {
    int t = blockIdx.x * blockDim.x + threadIdx.x;
    if (t >= NB * 1000) return;
    int r = t % 1000;
    int n = t / 1000;
    float S = 0.f;
    #pragma unroll 1
    for (int j = 0; j < 16; ++j) {
        u64 u = y6b[n * 16 + j] ^ fw2T[j * 1000 + r];
        chain64(S, u);
    }
    out[t] = __fadd_rn(__fmul_rn(S, (s7[r] < 0.f) ? -0.1f : 0.1f), b7[r]);
}

// ---------------- launch ----------------
extern "C" void kernel_launch(void* const* d_in, const int* in_sizes, int n_in,
                              void* d_out, int out_size, void* d_ws, size_t ws_size,
                              hipStream_t stream) {
    const float* x   = (const float*)d_in[0];
    const float* s0  = (const float*)d_in[1];
    const float* b0  = (const float*)d_in[2];
    const float* w1  = (const float*)d_in[3];
    const float* s1  = (const float*)d_in[4];
    const float* b1  = (const float*)d_in[5];
    const float* w2  = (const float*)d_in[6];
    const float* s2  = (const float*)d_in[7];
    const float* b2  = (const float*)d_in[8];
    const float* w3  = (const float*)d_in[9];
    const float* s3  = (const float*)d_in[10];
    const float* b3  = (const float*)d_in[11];
    const float* w4  = (const float*)d_in[12];
    const float* s4  = (const float*)d_in[13];
    const float* b4  = (const float*)d_in[14];
    const float* w5  = (const float*)d_in[15];
    const float* s5  = (const float*)d_in[16];
    const float* b5  = (const float*)d_in[17];
    const float* fw1 = (const float*)d_in[18];
    const float* s6  = (const float*)d_in[19];
    const float* b6  = (const float*)d_in[20];
    const float* fw2 = (const float*)d_in[21];
    const float* s7  = (const float*)d_in[22];
    const float* b7  = (const float*)d_in[23];

    u64* p = (u64*)d_ws;
    float* T64  = (float*)p; p += 64;    // 65 floats
    float* T128 = (float*)p; p += 128;   // 129 floats
    int* okflag = (int*)p;   p += 8;
    float* w1T = (float*)p; p += 3936;
    u64* w2T  = p; p += 41 * 64;
    u64* w3T  = p; p += 41 * 128;
    u64* w4T  = p; p += 82 * 128;
    u64* w5T  = p; p += 82 * 128;
    u64* fw1T = p; p += 156 * 1024;
    u64* fw2T = p; p += 16 * 1000;
    u64* a1   = p; p += (size_t)NB * P1;
    u64* a2   = p; p += (size_t)NB * P2;
    u64* a3   = p; p += (size_t)NB * P3 * 2;
    u64* a4   = p; p += (size_t)NB * P4 * 2;
    u64* a5   = p; p += (size_t)NB * C5 * 2;
    u64* a5F  = p; p += (size_t)NB * 156;
    u64* y6b  = p; p += (size_t)NB * 16;

    build_tab<<<1, 256, 0, stream>>>(T64, T128, okflag);
    pack_w1T<<<(3 * 41 * 64 + 255) / 256, 256, 0, stream>>>(w1, w1T);
    pack_wT<<<(64 * 41 + 255) / 256, 256, 0, stream>>>(w2, w2T, 64, 1);
    pack_wT<<<(128 * 41 + 255) / 256, 256, 0, stream>>>(w3, w3T, 128, 1);
    pack_wT<<<(128 * 82 + 255) / 256, 256, 0, stream>>>(w4, w4T, 128, 2);
    pack_wT<<<(128 * 82 + 255) / 256, 256, 0, stream>>>(w5, w5T, 128, 2);
    pack_fw1T<<<(156 * 1024 + 255) / 256, 256, 0, stream>>>(fw1, fw1T);
    pack_fw2T<<<(16 * 1000 + 255) / 256, 256, 0, stream>>>(fw2, fw2T);

    conv1_k<<<dim3(P1, NB), 64, 0, stream>>>(x, w1T, s0, b0, s1, b1, a1);
    bconv_tab<1, 3><<<dim3(P2, NB), 64, 0, stream>>>(a1, w2T, T64, okflag, s2, b2, a2, P1, P2);
    bconv_tab<1, 3><<<dim3(P3, NB), 128, 0, stream>>>(a2, w3T, T64, okflag, s3, b3, a3, P2, P3);
    bconv_tab<2, 3><<<dim3(P4, NB), 128, 0, stream>>>(a3, w4T, T128, okflag, s4, b4, a4, P3, P4);
    bconv_tab<2, 1><<<dim3(C5, NB), 128, 0, stream>>>(a4, w5T, T128, okflag, s5, b5, a5, P4, C5);
    repack_a5<<<(NB * 156 + 255) / 256, 256, 0, stream>>>(a5, a5F);
    fc1_k<<<dim3(16, NB), 64, 0, stream>>>(a5F, fw1T, s6, b6, y6b);
    fc2_k<<<(NB * 1000 + 255) / 256, 256, 0, stream>>>(y6b, fw2T, s7, b7, (float*)d_out);
}

// Round 13
// 2458.141 us; speedup vs baseline: 4.2601x; 3.2432x over previous
//
#include <hip/hip_runtime.h>
#include <cstdint>

typedef unsigned long long u64;
typedef unsigned int u32;

#define L_X 16000
#define NB  64
#define P1  5320   // conv1(15960) pool3
#define P2  1746   // conv2(5240) pool3
#define P3  555    // conv3(1666) pool3
#define P4  158    // conv4(475) pool3
#define C5  78     // conv5 out, no pool

// ---- exact scalar chain: A = fl(A + (bit ? -0.1f : +0.1f)), LSB-first ----
__device__ __forceinline__ void chain64(float& A, u64 u) {
    u32 w = (u32)u;
    #pragma unroll
    for (int j = 0; j < 32; ++j)
        A = __fadd_rn(A, __uint_as_float(0x3DCCCCCDu | ((w << (31 - j)) & 0x80000000u)));
    w = (u32)(u >> 32);
    #pragma unroll
    for (int j = 0; j < 32; ++j)
        A = __fadd_rn(A, __uint_as_float(0x3DCCCCCDu | ((w << (31 - j)) & 0x80000000u)));
}

// ---------------- packing kernels ----------------
__global__ void pack_w1T(const float* __restrict__ w1, float* __restrict__ w1T) {
    int t = blockIdx.x * blockDim.x + threadIdx.x;
    if (t >= 3 * 41 * 64) return;
    int co = t & 63;
    int rem = t >> 6;
    int k = rem % 41;
    int ci = rem / 41;
    w1T[t] = (w1[((size_t)co * 3 + ci) * 41 + k] < 0.f) ? -0.1f : 0.1f;
}

__global__ void pack_wT(const float* __restrict__ w, u64* __restrict__ wT,
                        int Co, int CIW) {
    int t = blockIdx.x * blockDim.x + threadIdx.x;
    if (t >= Co * 41 * CIW) return;
    int co = t % Co;
    int rem = t / Co;
    int h = rem % CIW;
    int k = rem / CIW;
    int CI = CIW * 64;
    u64 word = 0;
    for (int c = 0; c < 64; ++c)
        if (w[((size_t)co * CI + h * 64 + c) * 41 + k] < 0.f) word |= 1ull << c;
    wT[t] = word;
}

__global__ void pack_fw1T(const float* __restrict__ w, u64* __restrict__ wT) {
    int t = blockIdx.x * blockDim.x + threadIdx.x;
    if (t >= 156 * 1024) return;
    int row = t & 1023;
    int j = t >> 10;
    const float* base = w + (size_t)row * 9984 + j * 64;
    u64 word = 0;
    for (int c = 0; c < 64; ++c)
        if (base[c] < 0.f) word |= 1ull << c;
    wT[t] = word;
}

__global__ void pack_fw2T(const float* __restrict__ w, u64* __restrict__ wT) {
    int t = blockIdx.x * blockDim.x + threadIdx.x;
    if (t >= 16 * 1000) return;
    int row = t % 1000;
    int j = t / 1000;
    const float* base = w + (size_t)row * 1024 + j * 64;
    u64 word = 0;
    for (int c = 0; c < 64; ++c)
        if (base[c] < 0.f) word |= 1ull << c;
    wT[t] = word;
}

__global__ void repack_a5(const u64* __restrict__ a5, u64* __restrict__ a5F) {
    int t = blockIdx.x * blockDim.x + threadIdx.x;
    if (t >= NB * 156) return;
    int j = t % 156;
    int n = t / 156;
    u64 word = 0;
    #pragma unroll
    for (int c = 0; c < 64; ++c) {
        int jj = j * 64 + c;
        int chan = jj / 78;
        int tp = jj - chan * 78;
        u64 src = a5[((size_t)n * C5 + tp) * 2 + (chan >> 6)];
        word |= ((src >> (chan & 63)) & 1ull) << c;
    }
    a5F[t] = word;
}

// ---------------- conv1 + scale_bias + sign + pool3 ----------------
__global__ __launch_bounds__(64) void conv1_k(
        const float* __restrict__ x, const float* __restrict__ w1T,
        const float* __restrict__ s0, const float* __restrict__ b0,
        const float* __restrict__ s1, const float* __restrict__ b1,
        u64* __restrict__ a1) {
    int q = blockIdx.x;
    int n = blockIdx.y;
    int co = threadIdx.x;
    float sq0[3], bb0[3];
    #pragma unroll
    for (int ci = 0; ci < 3; ++ci) {
        sq0[ci] = (s0[ci] < 0.f) ? -0.1f : 0.1f;
        bb0[ci] = b0[ci];
    }
    float sq1 = (s1[co] < 0.f) ? -0.1f : 0.1f;
    float bb1 = b1[co];
    bool neg = true;
    for (int r = 0; r < 3; ++r) {
        int p = 3 * q + r;
        float S = 0.f;
        #pragma unroll 1
        for (int k = 0; k < 41; ++k) {
            float A = 0.f;
            #pragma unroll
            for (int ci = 0; ci < 3; ++ci) {
                float xv  = x[((size_t)n * 3 + ci) * L_X + p + k];
                float xsb = __fadd_rn(__fmul_rn(xv, sq0[ci]), bb0[ci]);
                float wf  = w1T[(ci * 41 + k) * 64 + co];
                A = __fadd_rn(A, __fmul_rn(xsb, wf));
            }
            S = __fadd_rn(S, A);
        }
        float pre = __fadd_rn(__fmul_rn(S, sq1), bb1);
        neg = neg && (pre < 0.f);
    }
    u64 word = __ballot(neg);
    if (co == 0) a1[(size_t)n * P1 + q] = word;
}

// ---------------- binary conv: popcount fast path + guarded exact fallback ----------------
// block = Co threads; grid (Lq, NB). abits_in: [(n*Lin + pos)*CIW + h]
// G = rigorous upper bound on |f32-chain pre - exact pre|; flagged waves rerun exact chain.
template <int CIW, int POOLK>
__global__ void bconv_g(const u64* __restrict__ abits_in, const u64* __restrict__ wT,
                        const float* __restrict__ s, const float* __restrict__ b,
                        u64* __restrict__ abits_out, int Lin, int Lq, double G) {
    constexpr int BITS = 41 * CIW * 64;
    int q = blockIdx.x;
    int n = blockIdx.y;
    int co = threadIdx.x;
    int Co = blockDim.x;
    int wave = co >> 6;
    int CoW = Co >> 6;
    float sqf = (s[co] < 0.f) ? -0.1f : 0.1f;
    float bf  = b[co];
    const u64* wp = wT + co;
    const u64* ap = abits_in + ((size_t)n * Lin + (size_t)POOLK * q) * CIW;

    // fast path: exact integer popcount accumulation
    int pc[POOLK];
    #pragma unroll
    for (int r = 0; r < POOLK; ++r) pc[r] = 0;
    #pragma unroll 1
    for (int k = 0; k < 41; ++k) {
        u64 wk[CIW];
        #pragma unroll
        for (int h = 0; h < CIW; ++h) wk[h] = wp[((size_t)k * CIW + h) * Co];
        const u64* ak = ap + (size_t)(2 * k) * CIW;
        #pragma unroll
        for (int r = 0; r < POOLK; ++r) {
            #pragma unroll
            for (int h = 0; h < CIW; ++h)
                pc[r] += (int)__popcll(ak[r * CIW + h] ^ wk[h]);
        }
    }
    // pre_exact = m * v^2 * sign(s) + b, v = (double)0.1f (exact)
    const double vv = (double)0.1f * (double)0.1f;
    double svv = (sqf < 0.f) ? -vv : vv;
    double bd = (double)bf;
    bool neg = true, flag = false;
    #pragma unroll
    for (int r = 0; r < POOLK; ++r) {
        double pre = (double)(BITS - 2 * pc[r]) * svv + bd;
        neg = neg && (pre < 0.0);
        flag = flag || (fabs(pre) < G);
    }

    // wave-uniform exact recompute when any lane-decision is inside the guard band
    if (__ballot(flag) != 0ull) {
        neg = true;
        for (int r = 0; r < POOLK; ++r) {
            float S = 0.f;
            #pragma unroll 1
            for (int k = 0; k < 41; ++k) {
                float A = 0.f;
                #pragma unroll
                for (int h = 0; h < CIW; ++h) {
                    u64 u = ap[(size_t)(2 * k + r) * CIW + h]
                          ^ wp[((size_t)k * CIW + h) * Co];
                    chain64(A, u);
                }
                S = __fadd_rn(S, A);
            }
            neg = neg && (__fadd_rn(__fmul_rn(S, sqf), bf) < 0.f);
        }
    }
    u64 word = __ballot(neg);
    if ((co & 63) == 0) abits_out[((size_t)n * Lq + q) * CoW + wave] = word;
}

// ---------------- fc1: single sequential chain over 9984 bits ----------------
__global__ __launch_bounds__(64) void fc1_k(
        const u64* __restrict__ a5F, const u64* __restrict__ fw1T,
        const float* __restrict__ s6, const float* __restrict__ b6,
        u64* __restrict__ y6b) {
    int g = blockIdx.x;
    int n = blockIdx.y;
    int lane = threadIdx.x;
    int row = g * 64 + lane;
    float S = 0.f;
    #pragma unroll 1
    for (int j = 0; j < 156; ++j) {
        u64 u = a5F[(size_t)n * 156 + j] ^ fw1T[(size_t)j * 1024 + row];
        chain64(S, u);
    }
    float pre = __fadd_rn(__fmul_rn(S, (s6[row] < 0.f) ? -0.1f : 0.1f), b6[row]);
    u64 word = __ballot(pre < 0.f);
    if (lane == 0) y6b[n * 16 + g] = word;
}

// ---------------- fc2: single chain over 1024 bits -> f32 out ----------------
__global__ void fc2_k(const u64* __restrict__ y6b, const u64* __restrict__ fw2T,
                      const float* __restrict__ s7, const float* __restrict__ b7,
                      float* __restrict__ out) {
    int t = blockIdx.x * blockDim.x + threadIdx.x;
    if (t >= NB * 1000) return;
    int r = t % 1000;
    int n = t / 1000;
    float S = 0.f;
    #pragma unroll 1
    for (int j = 0; j < 16; ++j) {
        u64 u = y6b[n * 16 + j] ^ fw2T[j * 1000 + r];
        chain64(S, u);
    }
    out[t] = __fadd_rn(__fmul_rn(S, (s7[r] < 0.f) ? -0.1f : 0.1f), b7[r]);
}

// ---------------- launch ----------------
extern "C" void kernel_launch(void* const* d_in, const int* in_sizes, int n_in,
                              void* d_out, int out_size, void* d_ws, size_t ws_size,
                              hipStream_t stream) {
    const float* x   = (const float*)d_in[0];
    const float* s0  = (const float*)d_in[1];
    const float* b0  = (const float*)d_in[2];
    const float* w1  = (const float*)d_in[3];
    const float* s1  = (const float*)d_in[4];
    const float* b1  = (const float*)d_in[5];
    const float* w2  = (const float*)d_in[6];
    const float* s2  = (const float*)d_in[7];
    const float* b2  = (const float*)d_in[8];
    const float* w3  = (const float*)d_in[9];
    const float* s3  = (const float*)d_in[10];
    const float* b3  = (const float*)d_in[11];
    const float* w4  = (const float*)d_in[12];
    const float* s4  = (const float*)d_in[13];
    const float* b4  = (const float*)d_in[14];
    const float* w5  = (const float*)d_in[15];
    const float* s5  = (const float*)d_in[16];
    const float* b5  = (const float*)d_in[17];
    const float* fw1 = (const float*)d_in[18];
    const float* s6  = (const float*)d_in[19];
    const float* b6  = (const float*)d_in[20];
    const float* fw2 = (const float*)d_in[21];
    const float* s7  = (const float*)d_in[22];
    const float* b7  = (const float*)d_in[23];

    u64* p = (u64*)d_ws;
    float* w1T = (float*)p; p += 3936;
    u64* w2T  = p; p += 41 * 64;
    u64* w3T  = p; p += 41 * 128;
    u64* w4T  = p; p += 82 * 128;
    u64* w5T  = p; p += 82 * 128;
    u64* fw1T = p; p += 156 * 1024;
    u64* fw2T = p; p += 16 * 1000;
    u64* a1   = p; p += (size_t)NB * P1;
    u64* a2   = p; p += (size_t)NB * P2;
    u64* a3   = p; p += (size_t)NB * P3 * 2;
    u64* a4   = p; p += (size_t)NB * P4 * 2;
    u64* a5   = p; p += (size_t)NB * C5 * 2;
    u64* a5F  = p; p += (size_t)NB * 156;
    u64* y6b  = p; p += (size_t)NB * 16;

    // rigorous |chain - exact| guard bounds (see analysis): CI=64 -> 1.30e-4, CI=128 -> 3.79e-4
    const double G64  = 2.0e-4;
    const double G128 = 5.0e-4;

    pack_w1T<<<(3 * 41 * 64 + 255) / 256, 256, 0, stream>>>(w1, w1T);
    pack_wT<<<(64 * 41 + 255) / 256, 256, 0, stream>>>(w2, w2T, 64, 1);
    pack_wT<<<(128 * 41 + 255) / 256, 256, 0, stream>>>(w3, w3T, 128, 1);
    pack_wT<<<(128 * 82 + 255) / 256, 256, 0, stream>>>(w4, w4T, 128, 2);
    pack_wT<<<(128 * 82 + 255) / 256, 256, 0, stream>>>(w5, w5T, 128, 2);
    pack_fw1T<<<(156 * 1024 + 255) / 256, 256, 0, stream>>>(fw1, fw1T);
    pack_fw2T<<<(16 * 1000 + 255) / 256, 256, 0, stream>>>(fw2, fw2T);

    conv1_k<<<dim3(P1, NB), 64, 0, stream>>>(x, w1T, s0, b0, s1, b1, a1);
    bconv_g<1, 3><<<dim3(P2, NB), 64, 0, stream>>>(a1, w2T, s2, b2, a2, P1, P2, G64);
    bconv_g<1, 3><<<dim3(P3, NB), 128, 0, stream>>>(a2, w3T, s3, b3, a3, P2, P3, G64);
    bconv_g<2, 3><<<dim3(P4, NB), 128, 0, stream>>>(a3, w4T, s4, b4, a4, P3, P4, G128);
    bconv_g<2, 1><<<dim3(C5, NB), 128, 0, stream>>>(a4, w5T, s5, b5, a5, P4, C5, G128);
    repack_a5<<<(NB * 156 + 255) / 256, 256, 0, stream>>>(a5, a5F);
    fc1_k<<<dim3(16, NB), 64, 0, stream>>>(a5F, fw1T, s6, b6, y6b);
    fc2_k<<<(NB * 1000 + 255) / 256, 256, 0, stream>>>(y6b, fw2T, s7, b7, (float*)d_out);
}

// Round 14
// 1786.481 us; speedup vs baseline: 5.8618x; 1.3760x over previous
//
#include <hip/hip_runtime.h>
#include <cstdint>

typedef unsigned long long u64;
typedef unsigned int u32;

#define L_X 16000
#define NB  64
#define P1  5320   // conv1(15960) pool3
#define P2  1746   // conv2(5240) pool3
#define P3  555    // conv3(1666) pool3
#define P4  158    // conv4(475) pool3
#define C5  78     // conv5 out, no pool

// ---- exact scalar chain: A = fl(A + (bit ? -0.1f : +0.1f)), LSB-first ----
__device__ __forceinline__ void chain64(float& A, u64 u) {
    u32 w = (u32)u;
    #pragma unroll
    for (int j = 0; j < 32; ++j)
        A = __fadd_rn(A, __uint_as_float(0x3DCCCCCDu | ((w << (31 - j)) & 0x80000000u)));
    w = (u32)(u >> 32);
    #pragma unroll
    for (int j = 0; j < 32; ++j)
        A = __fadd_rn(A, __uint_as_float(0x3DCCCCCDu | ((w << (31 - j)) & 0x80000000u)));
}

// ---------------- packing kernels ----------------
// conv1 weights -> bit words: pw1[co*2+{0,1}], bit idx = ci*41+k (LSB-first)
__global__ void pack_w1b(const float* __restrict__ w, u64* __restrict__ dst) {
    int co = blockIdx.x * blockDim.x + threadIdx.x;
    if (co >= 64) return;
    u64 lo = 0, hi = 0;
    for (int ci = 0; ci < 3; ++ci)
        for (int k = 0; k < 41; ++k) {
            int idx = ci * 41 + k;
            if (w[(co * 3 + ci) * 41 + k] < 0.f) {
                if (idx < 64) lo |= 1ull << idx;
                else          hi |= 1ull << (idx - 64);
            }
        }
    dst[co * 2] = lo;
    dst[co * 2 + 1] = hi;
}

__global__ void pack_wT(const float* __restrict__ w, u64* __restrict__ wT,
                        int Co, int CIW) {
    int t = blockIdx.x * blockDim.x + threadIdx.x;
    if (t >= Co * 41 * CIW) return;
    int co = t % Co;
    int rem = t / Co;
    int h = rem % CIW;
    int k = rem / CIW;
    int CI = CIW * 64;
    u64 word = 0;
    for (int c = 0; c < 64; ++c)
        if (w[((size_t)co * CI + h * 64 + c) * 41 + k] < 0.f) word |= 1ull << c;
    wT[t] = word;
}

__global__ void pack_fw1T(const float* __restrict__ w, u64* __restrict__ wT) {
    int t = blockIdx.x * blockDim.x + threadIdx.x;
    if (t >= 156 * 1024) return;
    int row = t & 1023;
    int j = t >> 10;
    const float* base = w + (size_t)row * 9984 + j * 64;
    u64 word = 0;
    for (int c = 0; c < 64; ++c)
        if (base[c] < 0.f) word |= 1ull << c;
    wT[t] = word;
}

__global__ void pack_fw2T(const float* __restrict__ w, u64* __restrict__ wT) {
    int t = blockIdx.x * blockDim.x + threadIdx.x;
    if (t >= 16 * 1000) return;
    int row = t % 1000;
    int j = t / 1000;
    const float* base = w + (size_t)row * 1024 + j * 64;
    u64 word = 0;
    for (int c = 0; c < 64; ++c)
        if (base[c] < 0.f) word |= 1ull << c;
    wT[t] = word;
}

__global__ void repack_a5(const u64* __restrict__ a5, u64* __restrict__ a5F) {
    int t = blockIdx.x * blockDim.x + threadIdx.x;
    if (t >= NB * 156) return;
    int j = t % 156;
    int n = t / 156;
    u64 word = 0;
    #pragma unroll
    for (int c = 0; c < 64; ++c) {
        int jj = j * 64 + c;
        int chan = jj / 78;
        int tp = jj - chan * 78;
        u64 src = a5[((size_t)n * C5 + tp) * 2 + (chan >> 6)];
        word |= ((src >> (chan & 63)) & 1ull) << c;
    }
    a5F[t] = word;
}

// ---------------- conv1 transposed: lane = q, loop co; y reused 64x ----------------
// grid (ceil(P1/64), NB), block 64. Exact float sequence == R6/R7:
// t_ci = +-fl(xsb*0.1f) (sign-symmetric RNE mul); A = t0; A=fl(A+t1); A=fl(A+t2); S=fl(S+A).
__global__ __launch_bounds__(64) void conv1_t(
        const float* __restrict__ x, const u64* __restrict__ pw1,
        const float* __restrict__ s0, const float* __restrict__ b0,
        const float* __restrict__ s1, const float* __restrict__ b1,
        u64* __restrict__ a1) {
    int lane = threadIdx.x;
    int q = blockIdx.x * 64 + lane;
    int n = blockIdx.y;
    bool valid = q < P1;
    int qc = valid ? q : P1 - 1;

    // y[ci][t] = fl(fl(fl(x*sq0)+b0)*0.1f) for x position 3*qc + t, t in [0,43)
    float y[3][43];
    #pragma unroll
    for (int ci = 0; ci < 3; ++ci) {
        float sq = (s0[ci] < 0.f) ? -0.1f : 0.1f;
        float bb = b0[ci];
        const float* bp = x + ((size_t)n * 3 + ci) * L_X + 3 * qc;
        #pragma unroll
        for (int t = 0; t < 43; ++t) {
            float xsb = __fadd_rn(__fmul_rn(bp[t], sq), bb);
            y[ci][t] = __fmul_rn(xsb, 0.1f);
        }
    }

    u64 word = 0;
    #pragma unroll 1
    for (int co = 0; co < 64; ++co) {
        u64 wlo = pw1[co * 2];       // wave-uniform -> scalar
        u64 whi = pw1[co * 2 + 1];
        float sq1 = (s1[co] < 0.f) ? -0.1f : 0.1f;
        float bb1 = b1[co];
        bool neg = true;
        #pragma unroll
        for (int r = 0; r < 3; ++r) {
            float S = 0.f;
            #pragma unroll
            for (int k = 0; k < 41; ++k) {
                // sign masks (scalar pipe): bit idx = ci*41+k
                u32 m0 = (u32)(wlo >> k) << 31;
                u32 m1 = (41 + k < 64) ? ((u32)(wlo >> (41 + k)) << 31)
                                       : ((u32)(whi >> (41 + k - 64)) << 31);
                u32 m2 = (u32)(whi >> (82 + k - 64)) << 31;
                float A = __uint_as_float(__float_as_uint(y[0][r + k]) ^ m0);
                A = __fadd_rn(A, __uint_as_float(__float_as_uint(y[1][r + k]) ^ m1));
                A = __fadd_rn(A, __uint_as_float(__float_as_uint(y[2][r + k]) ^ m2));
                S = __fadd_rn(S, A);
            }
            float pre = __fadd_rn(__fmul_rn(S, sq1), bb1);
            neg = neg && (pre < 0.f);
        }
        word |= (u64)(neg ? 1 : 0) << co;
    }
    if (valid) a1[(size_t)n * P1 + q] = word;
}

// ---------------- binary conv: popcount fast path + guarded exact fallback ----------------
template <int CIW, int POOLK>
__global__ void bconv_g(const u64* __restrict__ abits_in, const u64* __restrict__ wT,
                        const float* __restrict__ s, const float* __restrict__ b,
                        u64* __restrict__ abits_out, int Lin, int Lq, double G) {
    constexpr int BITS = 41 * CIW * 64;
    int q = blockIdx.x;
    int n = blockIdx.y;
    int co = threadIdx.x;
    int Co = blockDim.x;
    int wave = co >> 6;
    int CoW = Co >> 6;
    float sqf = (s[co] < 0.f) ? -0.1f : 0.1f;
    float bf  = b[co];
    const u64* wp = wT + co;
    const u64* ap = abits_in + ((size_t)n * Lin + (size_t)POOLK * q) * CIW;

    int pc[POOLK];
    #pragma unroll
    for (int r = 0; r < POOLK; ++r) pc[r] = 0;
    #pragma unroll 1
    for (int k = 0; k < 41; ++k) {
        u64 wk[CIW];
        #pragma unroll
        for (int h = 0; h < CIW; ++h) wk[h] = wp[((size_t)k * CIW + h) * Co];
        const u64* ak = ap + (size_t)(2 * k) * CIW;
        #pragma unroll
        for (int r = 0; r < POOLK; ++r) {
            #pragma unroll
            for (int h = 0; h < CIW; ++h)
                pc[r] += (int)__popcll(ak[r * CIW + h] ^ wk[h]);
        }
    }
    const double vv = (double)0.1f * (double)0.1f;
    double svv = (sqf < 0.f) ? -vv : vv;
    double bd = (double)bf;
    bool neg = true, flag = false;
    #pragma unroll
    for (int r = 0; r < POOLK; ++r) {
        double pre = (double)(BITS - 2 * pc[r]) * svv + bd;
        neg = neg && (pre < 0.0);
        flag = flag || (fabs(pre) < G);
    }
    if (__ballot(flag) != 0ull) {
        neg = true;
        for (int r = 0; r < POOLK; ++r) {
            float S = 0.f;
            #pragma unroll 1
            for (int k = 0; k < 41; ++k) {
                float A = 0.f;
                #pragma unroll
                for (int h = 0; h < CIW; ++h) {
                    u64 u = ap[(size_t)(2 * k + r) * CIW + h]
                          ^ wp[((size_t)k * CIW + h) * Co];
                    chain64(A, u);
                }
                S = __fadd_rn(S, A);
            }
            neg = neg && (__fadd_rn(__fmul_rn(S, sqf), bf) < 0.f);
        }
    }
    u64 word = __ballot(neg);
    if ((co & 63) == 0) abits_out[((size_t)n * Lq + q) * CoW + wave] = word;
}

// ---------------- fc1: single sequential chain over 9984 bits ----------------
__global__ __launch_bounds__(64) void fc1_k(
        const u64* __restrict__ a5F, const u64* __restrict__ fw1T,
        const float* __restrict__ s6, const float* __restrict__ b6,
        u64* __restrict__ y6b) {
    int g = blockIdx.x;
    int n = blockIdx.y;
    int lane = threadIdx.x;
    int row = g * 64 + lane;
    float S = 0.f;
    #pragma unroll 1
    for (int j = 0; j < 156; ++j) {
        u64 u = a5F[(size_t)n * 156 + j] ^ fw1T[(size_t)j * 1024 + row];
        chain64(S, u);
    }
    float pre = __fadd_rn(__fmul_rn(S, (s6[row] < 0.f) ? -0.1f : 0.1f), b6[row]);
    u64 word = __ballot(pre < 0.f);
    if (lane == 0) y6b[n * 16 + g] = word;
}

// ---------------- fc2: single chain over 1024 bits -> f32 out ----------------
__global__ void fc2_k(const u64* __restrict__ y6b, const u64* __restrict__ fw2T,
                      const float* __restrict__ s7, const float* __restrict__ b7,
                      float* __restrict__ out) {
    int t = blockIdx.x * blockDim.x + threadIdx.x;
    if (t >= NB * 1000) return;
    int r = t % 1000;
    int n = t / 1000;
    float S = 0.f;
    #pragma unroll 1
    for (int j = 0; j < 16; ++j) {
        u64 u = y6b[n * 16 + j] ^ fw2T[j * 1000 + r];
        chain64(S, u);
    }
    out[t] = __fadd_rn(__fmul_rn(S, (s7[r] < 0.f) ? -0.1f : 0.1f), b7[r]);
}

// ---------------- launch ----------------
extern "C" void kernel_launch(void* const* d_in, const int* in_sizes, int n_in,
                              void* d_out, int out_size, void* d_ws, size_t ws_size,
                              hipStream_t stream) {
    const float* x   = (const float*)d_in[0];
    const float* s0  = (const float*)d_in[1];
    const float* b0  = (const float*)d_in[2];
    const float* w1  = (const float*)d_in[3];
    const float* s1  = (const float*)d_in[4];
    const float* b1  = (const float*)d_in[5];
    const float* w2  = (const float*)d_in[6];
    const float* s2  = (const float*)d_in[7];
    const float* b2  = (const float*)d_in[8];
    const float* w3  = (const float*)d_in[9];
    const float* s3  = (const float*)d_in[10];
    const float* b3  = (const float*)d_in[11];
    const float* w4  = (const float*)d_in[12];
    const float* s4  = (const float*)d_in[13];
    const float* b4  = (const float*)d_in[14];
    const float* w5  = (const float*)d_in[15];
    const float* s5  = (const float*)d_in[16];
    const float* b5  = (const float*)d_in[17];
    const float* fw1 = (const float*)d_in[18];
    const float* s6  = (const float*)d_in[19];
    const float* b6  = (const float*)d_in[20];
    const float* fw2 = (const float*)d_in[21];
    const float* s7  = (const float*)d_in[22];
    const float* b7  = (const float*)d_in[23];

    u64* p = (u64*)d_ws;
    u64* pw1  = p; p += 128;
    u64* w2T  = p; p += 41 * 64;
    u64* w3T  = p; p += 41 * 128;
    u64* w4T  = p; p += 82 * 128;
    u64* w5T  = p; p += 82 * 128;
    u64* fw1T = p; p += 156 * 1024;
    u64* fw2T = p; p += 16 * 1000;
    u64* a1   = p; p += (size_t)NB * P1;
    u64* a2   = p; p += (size_t)NB * P2;
    u64* a3   = p; p += (size_t)NB * P3 * 2;
    u64* a4   = p; p += (size_t)NB * P4 * 2;
    u64* a5   = p; p += (size_t)NB * C5 * 2;
    u64* a5F  = p; p += (size_t)NB * 156;
    u64* y6b  = p; p += (size_t)NB * 16;

    const double G64  = 2.0e-4;
    const double G128 = 5.0e-4;

    pack_w1b<<<1, 64, 0, stream>>>(w1, pw1);
    pack_wT<<<(64 * 41 + 255) / 256, 256, 0, stream>>>(w2, w2T, 64, 1);
    pack_wT<<<(128 * 41 + 255) / 256, 256, 0, stream>>>(w3, w3T, 128, 1);
    pack_wT<<<(128 * 82 + 255) / 256, 256, 0, stream>>>(w4, w4T, 128, 2);
    pack_wT<<<(128 * 82 + 255) / 256, 256, 0, stream>>>(w5, w5T, 128, 2);
    pack_fw1T<<<(156 * 1024 + 255) / 256, 256, 0, stream>>>(fw1, fw1T);
    pack_fw2T<<<(16 * 1000 + 255) / 256, 256, 0, stream>>>(fw2, fw2T);

    conv1_t<<<dim3((P1 + 63) / 64, NB), 64, 0, stream>>>(x, pw1, s0, b0, s1, b1, a1);
    bconv_g<1, 3><<<dim3(P2, NB), 64, 0, stream>>>(a1, w2T, s2, b2, a2, P1, P2, G64);
    bconv_g<1, 3><<<dim3(P3, NB), 128, 0, stream>>>(a2, w3T, s3, b3, a3, P2, P3, G64);
    bconv_g<2, 3><<<dim3(P4, NB), 128, 0, stream>>>(a3, w4T, s4, b4, a4, P3, P4, G128);
    bconv_g<2, 1><<<dim3(C5, NB), 128, 0, stream>>>(a4, w5T, s5, b5, a5, P4, C5, G128);
    repack_a5<<<(NB * 156 + 255) / 256, 256, 0, stream>>>(a5, a5F);
    fc1_k<<<dim3(16, NB), 64, 0, stream>>>(a5F, fw1T, s6, b6, y6b);
    fc2_k<<<(NB * 1000 + 255) / 256, 256, 0, stream>>>(y6b, fw2T, s7, b7, (float*)d_out);
}

// Round 15
// 1727.597 us; speedup vs baseline: 6.0616x; 1.0341x over previous
//
#include <hip/hip_runtime.h>
#include <cstdint>

typedef unsigned long long u64;
typedef unsigned int u32;

#define L_X 16000
#define NB  64
#define P1  5320   // conv1(15960) pool3
#define P2  1746   // conv2(5240) pool3
#define P3  555    // conv3(1666) pool3
#define P4  158    // conv4(475) pool3
#define C5  78     // conv5 out, no pool

// ---- exact scalar chain: A = fl(A + (bit ? -0.1f : +0.1f)), LSB-first ----
__device__ __forceinline__ void chain64(float& A, u64 u) {
    u32 w = (u32)u;
    #pragma unroll
    for (int j = 0; j < 32; ++j)
        A = __fadd_rn(A, __uint_as_float(0x3DCCCCCDu | ((w << (31 - j)) & 0x80000000u)));
    w = (u32)(u >> 32);
    #pragma unroll
    for (int j = 0; j < 32; ++j)
        A = __fadd_rn(A, __uint_as_float(0x3DCCCCCDu | ((w << (31 - j)) & 0x80000000u)));
}

// ---------------- packing kernels ----------------
// conv1 weights as +-1.0f, layout w1f[co*123 + ci*41 + k]
__global__ void pack_w1f(const float* __restrict__ w1, float* __restrict__ w1f) {
    int t = blockIdx.x * blockDim.x + threadIdx.x;
    if (t >= 64 * 123) return;
    int co = t / 123;
    int j = t % 123;
    int ci = j / 41;
    int k = j % 41;
    w1f[t] = (w1[(co * 3 + ci) * 41 + k] < 0.f) ? -1.0f : 1.0f;
}

__global__ void pack_wT(const float* __restrict__ w, u64* __restrict__ wT,
                        int Co, int CIW) {
    int t = blockIdx.x * blockDim.x + threadIdx.x;
    if (t >= Co * 41 * CIW) return;
    int co = t % Co;
    int rem = t / Co;
    int h = rem % CIW;
    int k = rem / CIW;
    int CI = CIW * 64;
    u64 word = 0;
    for (int c = 0; c < 64; ++c)
        if (w[((size_t)co * CI + h * 64 + c) * 41 + k] < 0.f) word |= 1ull << c;
    wT[t] = word;
}

__global__ void pack_fw1T(const float* __restrict__ w, u64* __restrict__ wT) {
    int t = blockIdx.x * blockDim.x + threadIdx.x;
    if (t >= 156 * 1024) return;
    int row = t & 1023;
    int j = t >> 10;
    const float* base = w + (size_t)row * 9984 + j * 64;
    u64 word = 0;
    for (int c = 0; c < 64; ++c)
        if (base[c] < 0.f) word |= 1ull << c;
    wT[t] = word;
}

__global__ void pack_fw2T(const float* __restrict__ w, u64* __restrict__ wT) {
    int t = blockIdx.x * blockDim.x + threadIdx.x;
    if (t >= 16 * 1000) return;
    int row = t % 1000;
    int j = t / 1000;
    const float* base = w + (size_t)row * 1024 + j * 64;
    u64 word = 0;
    for (int c = 0; c < 64; ++c)
        if (base[c] < 0.f) word |= 1ull << c;
    wT[t] = word;
}

__global__ void repack_a5(const u64* __restrict__ a5, u64* __restrict__ a5F) {
    int t = blockIdx.x * blockDim.x + threadIdx.x;
    if (t >= NB * 156) return;
    int j = t % 156;
    int n = t / 156;
    u64 word = 0;
    #pragma unroll
    for (int c = 0; c < 64; ++c) {
        int jj = j * 64 + c;
        int chan = jj / 78;
        int tp = jj - chan * 78;
        u64 src = a5[((size_t)n * C5 + tp) * 2 + (chan >> 6)];
        word |= ((src >> (chan & 63)) & 1ull) << c;
    }
    a5F[t] = word;
}

// ---------------- conv1 transposed: lane = q, loop co; y register-resident ----------------
// Exact float sequence == R6/R7: t_ci = +-y (sign-exact), A-chain via fma(y, +-1.0f, A)
// = fl(A +- y); S = fl(S + A).  __launch_bounds__(64,1): no VGPR cap -> no remat/spill.
__global__ __launch_bounds__(64, 1) void conv1_t(
        const float* __restrict__ x, const float* __restrict__ w1f,
        const float* __restrict__ s0, const float* __restrict__ b0,
        const float* __restrict__ s1, const float* __restrict__ b1,
        u64* __restrict__ a1) {
    int lane = threadIdx.x;
    int q = blockIdx.x * 64 + lane;
    int n = blockIdx.y;
    bool valid = q < P1;
    int qc = valid ? q : P1 - 1;

    // y[ci][t] = fl(fl(fl(x*sq0)+b0)*0.1f) for x position 3*qc + t, t in [0,43)
    float y[3][43];
    #pragma unroll
    for (int ci = 0; ci < 3; ++ci) {
        float sq = (s0[ci] < 0.f) ? -0.1f : 0.1f;
        float bb = b0[ci];
        const float* bp = x + ((size_t)n * 3 + ci) * L_X + 3 * qc;
        #pragma unroll
        for (int t = 0; t < 43; ++t) {
            float xsb = __fadd_rn(__fmul_rn(bp[t], sq), bb);
            y[ci][t] = __fmul_rn(xsb, 0.1f);
        }
    }

    u64 word = 0;
    #pragma unroll 1
    for (int co = 0; co < 64; ++co) {
        const float* wrow = w1f + co * 123;      // wave-uniform -> scalar loads
        float sq1 = (s1[co] < 0.f) ? -0.1f : 0.1f;
        float bb1 = b1[co];
        bool neg = true;
        #pragma unroll
        for (int r = 0; r < 3; ++r) {
            float S = 0.f;
            #pragma unroll
            for (int k = 0; k < 41; ++k) {
                float A = __fmul_rn(y[0][r + k], wrow[k]);        // = +-y0 exactly
                A = __fmaf_rn(y[1][r + k], wrow[41 + k], A);      // = fl(A +- y1)
                A = __fmaf_rn(y[2][r + k], wrow[82 + k], A);      // = fl(A +- y2)
                S = __fadd_rn(S, A);
            }
            float pre = __fadd_rn(__fmul_rn(S, sq1), bb1);
            neg = neg && (pre < 0.f);
        }
        word |= (u64)(neg ? 1 : 0) << co;
    }
    if (valid) a1[(size_t)n * P1 + q] = word;
}

// ---------------- binary conv: popcount fast path + per-r guarded exact fallback ----------------
template <int CIW, int POOLK>
__global__ void bconv_g(const u64* __restrict__ abits_in, const u64* __restrict__ wT,
                        const float* __restrict__ s, const float* __restrict__ b,
                        u64* __restrict__ abits_out, int Lin, int Lq, double G) {
    constexpr int BITS = 41 * CIW * 64;
    int q = blockIdx.x;
    int n = blockIdx.y;
    int co = threadIdx.x;
    int Co = blockDim.x;
    int wave = co >> 6;
    int CoW = Co >> 6;
    float sqf = (s[co] < 0.f) ? -0.1f : 0.1f;
    float bf  = b[co];
    const u64* wp = wT + co;
    const u64* ap = abits_in + ((size_t)n * Lin + (size_t)POOLK * q) * CIW;

    int pc[POOLK];
    #pragma unroll
    for (int r = 0; r < POOLK; ++r) pc[r] = 0;
    #pragma unroll 1
    for (int k = 0; k < 41; ++k) {
        u64 wk[CIW];
        #pragma unroll
        for (int h = 0; h < CIW; ++h) wk[h] = wp[((size_t)k * CIW + h) * Co];
        const u64* ak = ap + (size_t)(2 * k) * CIW;
        #pragma unroll
        for (int r = 0; r < POOLK; ++r) {
            #pragma unroll
            for (int h = 0; h < CIW; ++h)
                pc[r] += (int)__popcll(ak[r * CIW + h] ^ wk[h]);
        }
    }
    const double vv = (double)0.1f * (double)0.1f;
    double svv = (sqf < 0.f) ? -vv : vv;
    double bd = (double)bf;
    bool negr[POOLK];
    bool flagr[POOLK];
    #pragma unroll
    for (int r = 0; r < POOLK; ++r) {
        double pre = (double)(BITS - 2 * pc[r]) * svv + bd;
        negr[r] = (pre < 0.0);
        flagr[r] = (fabs(pre) < G);
    }
    // per-r wave-uniform exact recompute, only for flagged pool positions
    #pragma unroll
    for (int r = 0; r < POOLK; ++r) {
        if (__ballot(flagr[r]) != 0ull) {
            float S = 0.f;
            #pragma unroll 1
            for (int k = 0; k < 41; ++k) {
                float A = 0.f;
                #pragma unroll
                for (int h = 0; h < CIW; ++h) {
                    u64 u = ap[(size_t)(2 * k + r) * CIW + h]
                          ^ wp[((size_t)k * CIW + h) * Co];
                    chain64(A, u);
                }
                S = __fadd_rn(S, A);
            }
            negr[r] = (__fadd_rn(__fmul_rn(S, sqf), bf) < 0.f);
        }
    }
    bool neg = true;
    #pragma unroll
    for (int r = 0; r < POOLK; ++r) neg = neg && negr[r];
    u64 word = __ballot(neg);
    if ((co & 63) == 0) abits_out[((size_t)n * Lq + q) * CoW + wave] = word;
}

// ---------------- fc1: single sequential chain over 9984 bits ----------------
__global__ __launch_bounds__(64) void fc1_k(
        const u64* __restrict__ a5F, const u64* __restrict__ fw1T,
        const float* __restrict__ s6, const float* __restrict__ b6,
        u64* __restrict__ y6b) {
    int g = blockIdx.x;
    int n = blockIdx.y;
    int lane = threadIdx.x;
    int row = g * 64 + lane;
    float S = 0.f;
    #pragma unroll 1
    for (int j = 0; j < 156; ++j) {
        u64 u = a5F[(size_t)n * 156 + j] ^ fw1T[(size_t)j * 1024 + row];
        chain64(S, u);
    }
    float pre = __fadd_rn(__fmul_rn(S, (s6[row] < 0.f) ? -0.1f : 0.1f), b6[row]);
    u64 word = __ballot(pre < 0.f);
    if (lane == 0) y6b[n * 16 + g] = word;
}

// ---------------- fc2: single chain over 1024 bits -> f32 out ----------------
__global__ void fc2_k(const u64* __restrict__ y6b, const u64* __restrict__ fw2T,
                      const float* __restrict__ s7, const float* __restrict__ b7,
                      float* __restrict__ out) {
    int t = blockIdx.x * blockDim.x + threadIdx.x;
    if (t >= NB * 1000) return;
    int r = t % 1000;
    int n = t / 1000;
    float S = 0.f;
    #pragma unroll 1
    for (int j = 0; j < 16; ++j) {
        u64 u = y6b[n * 16 + j] ^ fw2T[j * 1000 + r];
        chain64(S, u);
    }
    out[t] = __fadd_rn(__fmul_rn(S, (s7[r] < 0.f) ? -0.1f : 0.1f), b7[r]);
}

// ---------------- launch ----------------
extern "C" void kernel_launch(void* const* d_in, const int* in_sizes, int n_in,
                              void* d_out, int out_size, void* d_ws, size_t ws_size,
                              hipStream_t stream) {
    const float* x   = (const float*)d_in[0];
    const float* s0  = (const float*)d_in[1];
    const float* b0  = (const float*)d_in[2];
    const float* w1  = (const float*)d_in[3];
    const float* s1  = (const float*)d_in[4];
    const float* b1  = (const float*)d_in[5];
    const float* w2  = (const float*)d_in[6];
    const float* s2  = (const float*)d_in[7];
    const float* b2  = (const float*)d_in[8];
    const float* w3  = (const float*)d_in[9];
    const float* s3  = (const float*)d_in[10];
    const float* b3  = (const float*)d_in[11];
    const float* w4  = (const float*)d_in[12];
    const float* s4  = (const float*)d_in[13];
    const float* b4  = (const float*)d_in[14];
    const float* w5  = (const float*)d_in[15];
    const float* s5  = (const float*)d_in[16];
    const float* b5  = (const float*)d_in[17];
    const float* fw1 = (const float*)d_in[18];
    const float* s6  = (const float*)d_in[19];
    const float* b6  = (const float*)d_in[20];
    const float* fw2 = (const float*)d_in[21];
    const float* s7  = (const float*)d_in[22];
    const float* b7  = (const float*)d_in[23];

    u64* p = (u64*)d_ws;
    float* w1f = (float*)p; p += 3936;   // 64*123 floats
    u64* w2T  = p; p += 41 * 64;
    u64* w3T  = p; p += 41 * 128;
    u64* w4T  = p; p += 82 * 128;
    u64* w5T  = p; p += 82 * 128;
    u64* fw1T = p; p += 156 * 1024;
    u64* fw2T = p; p += 16 * 1000;
    u64* a1   = p; p += (size_t)NB * P1;
    u64* a2   = p; p += (size_t)NB * P2;
    u64* a3   = p; p += (size_t)NB * P3 * 2;
    u64* a4   = p; p += (size_t)NB * P4 * 2;
    u64* a5   = p; p += (size_t)NB * C5 * 2;
    u64* a5F  = p; p += (size_t)NB * 156;
    u64* y6b  = p; p += (size_t)NB * 16;

    const double G64  = 2.0e-4;
    const double G128 = 5.0e-4;

    pack_w1f<<<(64 * 123 + 255) / 256, 256, 0, stream>>>(w1, w1f);
    pack_wT<<<(64 * 41 + 255) / 256, 256, 0, stream>>>(w2, w2T, 64, 1);
    pack_wT<<<(128 * 41 + 255) / 256, 256, 0, stream>>>(w3, w3T, 128, 1);
    pack_wT<<<(128 * 82 + 255) / 256, 256, 0, stream>>>(w4, w4T, 128, 2);
    pack_wT<<<(128 * 82 + 255) / 256, 256, 0, stream>>>(w5, w5T, 128, 2);
    pack_fw1T<<<(156 * 1024 + 255) / 256, 256, 0, stream>>>(fw1, fw1T);
    pack_fw2T<<<(16 * 1000 + 255) / 256, 256, 0, stream>>>(fw2, fw2T);

    conv1_t<<<dim3((P1 + 63) / 64, NB), 64, 0, stream>>>(x, w1f, s0, b0, s1, b1, a1);
    bconv_g<1, 3><<<dim3(P2, NB), 64, 0, stream>>>(a1, w2T, s2, b2, a2, P1, P2, G64);
    bconv_g<1, 3><<<dim3(P3, NB), 128, 0, stream>>>(a2, w3T, s3, b3, a3, P2, P3, G64);
    bconv_g<2, 3><<<dim3(P4, NB), 128, 0, stream>>>(a3, w4T, s4, b4, a4, P3, P4, G128);
    bconv_g<2, 1><<<dim3(C5, NB), 128, 0, stream>>>(a4, w5T, s5, b5, a5, P4, C5, G128);
    repack_a5<<<(NB * 156 + 255) / 256, 256, 0, stream>>>(a5, a5F);
    fc1_k<<<dim3(16, NB), 64, 0, stream>>>(a5F, fw1T, s6, b6, y6b);
    fc2_k<<<(NB * 1000 + 255) / 256, 256, 0, stream>>>(y6b, fw2T, s7, b7, (float*)d_out);
}

// Round 16
// 1655.788 us; speedup vs baseline: 6.3245x; 1.0434x over previous
//
#include <hip/hip_runtime.h>
#include <cstdint>

typedef unsigned long long u64;
typedef unsigned int u32;

#define L_X 16000
#define NB  64
#define P1  5320   // conv1(15960) pool3
#define P2  1746   // conv2(5240) pool3
#define P3  555    // conv3(1666) pool3
#define P4  158    // conv4(475) pool3
#define C5  78     // conv5 out, no pool

// ---- exact scalar chain: A = fl(A + (bit ? -0.1f : +0.1f)), LSB-first ----
__device__ __forceinline__ void chain64(float& A, u64 u) {
    u32 w = (u32)u;
    #pragma unroll
    for (int j = 0; j < 32; ++j)
        A = __fadd_rn(A, __uint_as_float(0x3DCCCCCDu | ((w << (31 - j)) & 0x80000000u)));
    w = (u32)(u >> 32);
    #pragma unroll
    for (int j = 0; j < 32; ++j)
        A = __fadd_rn(A, __uint_as_float(0x3DCCCCCDu | ((w << (31 - j)) & 0x80000000u)));
}

// ---------------- packing kernels ----------------
// conv1 weights -> bit words: pw1[co*2+{0,1}], bit idx = ci*41+k (LSB-first)
__global__ void pack_w1b(const float* __restrict__ w, u64* __restrict__ dst) {
    int co = blockIdx.x * blockDim.x + threadIdx.x;
    if (co >= 64) return;
    u64 lo = 0, hi = 0;
    for (int ci = 0; ci < 3; ++ci)
        for (int k = 0; k < 41; ++k) {
            int idx = ci * 41 + k;
            if (w[(co * 3 + ci) * 41 + k] < 0.f) {
                if (idx < 64) lo |= 1ull << idx;
                else          hi |= 1ull << (idx - 64);
            }
        }
    dst[co * 2] = lo;
    dst[co * 2 + 1] = hi;
}

__global__ void pack_wT(const float* __restrict__ w, u64* __restrict__ wT,
                        int Co, int CIW) {
    int t = blockIdx.x * blockDim.x + threadIdx.x;
    if (t >= Co * 41 * CIW) return;
    int co = t % Co;
    int rem = t / Co;
    int h = rem % CIW;
    int k = rem / CIW;
    int CI = CIW * 64;
    u64 word = 0;
    for (int c = 0; c < 64; ++c)
        if (w[((size_t)co * CI + h * 64 + c) * 41 + k] < 0.f) word |= 1ull << c;
    wT[t] = word;
}

__global__ void pack_fw1T(const float* __restrict__ w, u64* __restrict__ wT) {
    int t = blockIdx.x * blockDim.x + threadIdx.x;
    if (t >= 156 * 1024) return;
    int row = t & 1023;
    int j = t >> 10;
    const float* base = w + (size_t)row * 9984 + j * 64;
    u64 word = 0;
    for (int c = 0; c < 64; ++c)
        if (base[c] < 0.f) word |= 1ull << c;
    wT[t] = word;
}

__global__ void pack_fw2T(const float* __restrict__ w, u64* __restrict__ wT) {
    int t = blockIdx.x * blockDim.x + threadIdx.x;
    if (t >= 16 * 1000) return;
    int row = t % 1000;
    int j = t / 1000;
    const float* base = w + (size_t)row * 1024 + j * 64;
    u64 word = 0;
    for (int c = 0; c < 64; ++c)
        if (base[c] < 0.f) word |= 1ull << c;
    wT[t] = word;
}

__global__ void repack_a5(const u64* __restrict__ a5, u64* __restrict__ a5F) {
    int t = blockIdx.x * blockDim.x + threadIdx.x;
    if (t >= NB * 156) return;
    int j = t % 156;
    int n = t / 156;
    u64 word = 0;
    #pragma unroll
    for (int c = 0; c < 64; ++c) {
        int jj = j * 64 + c;
        int chan = jj / 78;
        int tp = jj - chan * 78;
        u64 src = a5[((size_t)n * C5 + tp) * 2 + (chan >> 6)];
        word |= ((src >> (chan & 63)) & 1ull) << c;
    }
    a5F[t] = word;
}

// static-index bit extract from 4 scalar words (idx compile-time after unroll)
__device__ __forceinline__ u32 bit_of(u32 a, u32 b, u32 c, u32 d, int idx) {
    u32 w = (idx < 32) ? a : (idx < 64) ? b : (idx < 96) ? c : d;
    return (w >> (idx & 31)) & 1u;
}

// ---------------- conv1: lane = q, loop co; packed-bit SGPR weights + fma ----------------
// Exact float sequence == R14/R15 (both refcheck'd): A = (+-y0); A = fl(A +- y1);
// A = fl(A +- y2); S = fl(S + A); pre = fl(fl(S*sq1)+b1). Weights +-1.0f synthesized
// in SALU from packed bits (readfirstlane -> SGPR); inner loop has NO memory ops.
__global__ __launch_bounds__(64, 1) void conv1_t(
        const float* __restrict__ x, const u64* __restrict__ pw1,
        const float* __restrict__ s0, const float* __restrict__ b0,
        const float* __restrict__ s1, const float* __restrict__ b1,
        u64* __restrict__ a1) {
    int lane = threadIdx.x;
    int q = blockIdx.x * 64 + lane;
    int n = blockIdx.y;
    bool valid = q < P1;
    int qc = valid ? q : P1 - 1;

    // y[ci][t] = fl(fl(fl(x*sq0)+b0)*0.1f) for x position 3*qc + t, t in [0,43)
    float y[3][43];
    #pragma unroll
    for (int ci = 0; ci < 3; ++ci) {
        float sq = (s0[ci] < 0.f) ? -0.1f : 0.1f;
        float bb = b0[ci];
        const float* bp = x + ((size_t)n * 3 + ci) * L_X + 3 * qc;
        #pragma unroll
        for (int t = 0; t < 43; ++t) {
            float xsb = __fadd_rn(__fmul_rn(bp[t], sq), bb);
            y[ci][t] = __fmul_rn(xsb, 0.1f);
        }
    }

    u64 word = 0;
    #pragma unroll 1
    for (int co = 0; co < 64; ++co) {
        u64 wlo = pw1[co * 2];
        u64 whi = pw1[co * 2 + 1];
        // wave-uniform -> force SGPR so weight synthesis runs on the scalar pipe
        u32 wa = __builtin_amdgcn_readfirstlane((u32)wlo);
        u32 wb = __builtin_amdgcn_readfirstlane((u32)(wlo >> 32));
        u32 wc = __builtin_amdgcn_readfirstlane((u32)whi);
        u32 wd = __builtin_amdgcn_readfirstlane((u32)(whi >> 32));
        float sq1 = (s1[co] < 0.f) ? -0.1f : 0.1f;
        float bb1 = b1[co];
        float S[3] = {0.f, 0.f, 0.f};
        #pragma unroll
        for (int k = 0; k < 41; ++k) {
            // +-1.0f weights, computed once per k (hoisted out of r loop), SALU
            float wf0 = __uint_as_float(0x3F800000u | (bit_of(wa, wb, wc, wd, k) << 31));
            float wf1 = __uint_as_float(0x3F800000u | (bit_of(wa, wb, wc, wd, 41 + k) << 31));
            float wf2 = __uint_as_float(0x3F800000u | (bit_of(wa, wb, wc, wd, 82 + k) << 31));
            #pragma unroll
            for (int r = 0; r < 3; ++r) {
                float A = __fmul_rn(y[0][r + k], wf0);       // = +-y0 exactly
                A = __fmaf_rn(y[1][r + k], wf1, A);          // = fl(A +- y1)
                A = __fmaf_rn(y[2][r + k], wf2, A);          // = fl(A +- y2)
                S[r] = __fadd_rn(S[r], A);
            }
        }
        bool neg = true;
        #pragma unroll
        for (int r = 0; r < 3; ++r) {
            float pre = __fadd_rn(__fmul_rn(S[r], sq1), bb1);
            neg = neg && (pre < 0.f);
        }
        word |= (u64)(neg ? 1 : 0) << co;
    }
    if (valid) a1[(size_t)n * P1 + q] = word;
}

// ---------------- binary conv: popcount fast path + per-r guarded exact fallback ----------------
template <int CIW, int POOLK>
__global__ void bconv_g(const u64* __restrict__ abits_in, const u64* __restrict__ wT,
                        const float* __restrict__ s, const float* __restrict__ b,
                        u64* __restrict__ abits_out, int Lin, int Lq, double G) {
    constexpr int BITS = 41 * CIW * 64;
    int q = blockIdx.x;
    int n = blockIdx.y;
    int co = threadIdx.x;
    int Co = blockDim.x;
    int wave = co >> 6;
    int CoW = Co >> 6;
    float sqf = (s[co] < 0.f) ? -0.1f : 0.1f;
    float bf  = b[co];
    const u64* wp = wT + co;
    const u64* ap = abits_in + ((size_t)n * Lin + (size_t)POOLK * q) * CIW;

    int pc[POOLK];
    #pragma unroll
    for (int r = 0; r < POOLK; ++r) pc[r] = 0;
    #pragma unroll 1
    for (int k = 0; k < 41; ++k) {
        u64 wk[CIW];
        #pragma unroll
        for (int h = 0; h < CIW; ++h) wk[h] = wp[((size_t)k * CIW + h) * Co];
        const u64* ak = ap + (size_t)(2 * k) * CIW;
        #pragma unroll
        for (int r = 0; r < POOLK; ++r) {
            #pragma unroll
            for (int h = 0; h < CIW; ++h)
                pc[r] += (int)__popcll(ak[r * CIW + h] ^ wk[h]);
        }
    }
    const double vv = (double)0.1f * (double)0.1f;
    double svv = (sqf < 0.f) ? -vv : vv;
    double bd = (double)bf;
    bool negr[POOLK];
    bool flagr[POOLK];
    #pragma unroll
    for (int r = 0; r < POOLK; ++r) {
        double pre = (double)(BITS - 2 * pc[r]) * svv + bd;
        negr[r] = (pre < 0.0);
        flagr[r] = (fabs(pre) < G);
    }
    #pragma unroll
    for (int r = 0; r < POOLK; ++r) {
        if (__ballot(flagr[r]) != 0ull) {
            float S = 0.f;
            #pragma unroll 1
            for (int k = 0; k < 41; ++k) {
                float A = 0.f;
                #pragma unroll
                for (int h = 0; h < CIW; ++h) {
                    u64 u = ap[(size_t)(2 * k + r) * CIW + h]
                          ^ wp[((size_t)k * CIW + h) * Co];
                    chain64(A, u);
                }
                S = __fadd_rn(S, A);
            }
            negr[r] = (__fadd_rn(__fmul_rn(S, sqf), bf) < 0.f);
        }
    }
    bool neg = true;
    #pragma unroll
    for (int r = 0; r < POOLK; ++r) neg = neg && negr[r];
    u64 word = __ballot(neg);
    if ((co & 63) == 0) abits_out[((size_t)n * Lq + q) * CoW + wave] = word;
}

// ---------------- fc1: single sequential chain over 9984 bits ----------------
__global__ __launch_bounds__(64) void fc1_k(
        const u64* __restrict__ a5F, const u64* __restrict__ fw1T,
        const float* __restrict__ s6, const float* __restrict__ b6,
        u64* __restrict__ y6b) {
    int g = blockIdx.x;
    int n = blockIdx.y;
    int lane = threadIdx.x;
    int row = g * 64 + lane;
    float S = 0.f;
    #pragma unroll 1
    for (int j = 0; j < 156; ++j) {
        u64 u = a5F[(size_t)n * 156 + j] ^ fw1T[(size_t)j * 1024 + row];
        chain64(S, u);
    }
    float pre = __fadd_rn(__fmul_rn(S, (s6[row] < 0.f) ? -0.1f : 0.1f), b6[row]);
    u64 word = __ballot(pre < 0.f);
    if (lane == 0) y6b[n * 16 + g] = word;
}

// ---------------- fc2: single chain over 1024 bits -> f32 out ----------------
__global__ void fc2_k(const u64* __restrict__ y6b, const u64* __restrict__ fw2T,
                      const float* __restrict__ s7, const float* __restrict__ b7,
                      float* __restrict__ out) {
    int t = blockIdx.x * blockDim.x + threadIdx.x;
    if (t >= NB * 1000) return;
    int r = t % 1000;
    int n = t / 1000;
    float S = 0.f;
    #pragma unroll 1
    for (int j = 0; j < 16; ++j) {
        u64 u = y6b[n * 16 + j] ^ fw2T[j * 1000 + r];
        chain64(S, u);
    }
    out[t] = __fadd_rn(__fmul_rn(S, (s7[r] < 0.f) ? -0.1f : 0.1f), b7[r]);
}

// ---------------- launch ----------------
extern "C" void kernel_launch(void* const* d_in, const int* in_sizes, int n_in,
                              void* d_out, int out_size, void* d_ws, size_t ws_size,
                              hipStream_t stream) {
    const float* x   = (const float*)d_in[0];
    const float* s0  = (const float*)d_in[1];
    const float* b0  = (const float*)d_in[2];
    const float* w1  = (const float*)d_in[3];
    const float* s1  = (const float*)d_in[4];
    const float* b1  = (const float*)d_in[5];
    const float* w2  = (const float*)d_in[6];
    const float* s2  = (const float*)d_in[7];
    const float* b2  = (const float*)d_in[8];
    const float* w3  = (const float*)d_in[9];
    const float* s3  = (const float*)d_in[10];
    const float* b3  = (const float*)d_in[11];
    const float* w4  = (const float*)d_in[12];
    const float* s4  = (const float*)d_in[13];
    const float* b4  = (const float*)d_in[14];
    const float* w5  = (const float*)d_in[15];
    const float* s5  = (const float*)d_in[16];
    const float* b5  = (const float*)d_in[17];
    const float* fw1 = (const float*)d_in[18];
    const float* s6  = (const float*)d_in[19];
    const float* b6  = (const float*)d_in[20];
    const float* fw2 = (const float*)d_in[21];
    const float* s7  = (const float*)d_in[22];
    const float* b7  = (const float*)d_in[23];

    u64* p = (u64*)d_ws;
    u64* pw1  = p; p += 128;
    u64* w2T  = p; p += 41 * 64;
    u64* w3T  = p; p += 41 * 128;
    u64* w4T  = p; p += 82 * 128;
    u64* w5T  = p; p += 82 * 128;
    u64* fw1T = p; p += 156 * 1024;
    u64* fw2T = p; p += 16 * 1000;
    u64* a1   = p; p += (size_t)NB * P1;
    u64* a2   = p; p += (size_t)NB * P2;
    u64* a3   = p; p += (size_t)NB * P3 * 2;
    u64* a4   = p; p += (size_t)NB * P4 * 2;
    u64* a5   = p; p += (size_t)NB * C5 * 2;
    u64* a5F  = p; p += (size_t)NB * 156;
    u64* y6b  = p; p += (size_t)NB * 16;

    const double G64  = 2.0e-4;
    const double G128 = 5.0e-4;

    pack_w1b<<<1, 64, 0, stream>>>(w1, pw1);
    pack_wT<<<(64 * 41 + 255) / 256, 256, 0, stream>>>(w2, w2T, 64, 1);
    pack_wT<<<(128 * 41 + 255) / 256, 256, 0, stream>>>(w3, w3T, 128, 1);
    pack_wT<<<(128 * 82 + 255) / 256, 256, 0, stream>>>(w4, w4T, 128, 2);
    pack_wT<<<(128 * 82 + 255) / 256, 256, 0, stream>>>(w5, w5T, 128, 2);
    pack_fw1T<<<(156 * 1024 + 255) / 256, 256, 0, stream>>>(fw1, fw1T);
    pack_fw2T<<<(16 * 1000 + 255) / 256, 256, 0, stream>>>(fw2, fw2T);

    conv1_t<<<dim3((P1 + 63) / 64, NB), 64, 0, stream>>>(x, pw1, s0, b0, s1, b1, a1);
    bconv_g<1, 3><<<dim3(P2, NB), 64, 0, stream>>>(a1, w2T, s2, b2, a2, P1, P2, G64);
    bconv_g<1, 3><<<dim3(P3, NB), 128, 0, stream>>>(a2, w3T, s3, b3, a3, P2, P3, G64);
    bconv_g<2, 3><<<dim3(P4, NB), 128, 0, stream>>>(a3, w4T, s4, b4, a4, P3, P4, G128);
    bconv_g<2, 1><<<dim3(C5, NB), 128, 0, stream>>>(a4, w5T, s5, b5, a5, P4, C5, G128);
    repack_a5<<<(NB * 156 + 255) / 256, 256, 0, stream>>>(a5, a5F);
    fc1_k<<<dim3(16, NB), 64, 0, stream>>>(a5F, fw1T, s6, b6, y6b);
    fc2_k<<<(NB * 1000 + 255) / 256, 256, 0, stream>>>(y6b, fw2T, s7, b7, (float*)d_out);
}

// Round 17
// 1107.122 us; speedup vs baseline: 9.4588x; 1.4956x over previous
//
#include <hip/hip_runtime.h>
#include <cstdint>

typedef unsigned long long u64;
typedef unsigned int u32;

#define L_X 16000
#define NB  64
#define P1  5320   // conv1(15960) pool3
#define P2  1746   // conv2(5240) pool3
#define P3  555    // conv3(1666) pool3
#define P4  158    // conv4(475) pool3
#define C5  78     // conv5 out, no pool

// ---- exact scalar chain: A = fl(A + (bit ? -0.1f : +0.1f)), LSB-first ----
__device__ __forceinline__ void chain64(float& A, u64 u) {
    u32 w = (u32)u;
    #pragma unroll
    for (int j = 0; j < 32; ++j)
        A = __fadd_rn(A, __uint_as_float(0x3DCCCCCDu | ((w << (31 - j)) & 0x80000000u)));
    w = (u32)(u >> 32);
    #pragma unroll
    for (int j = 0; j < 32; ++j)
        A = __fadd_rn(A, __uint_as_float(0x3DCCCCCDu | ((w << (31 - j)) & 0x80000000u)));
}

// ---------------- packing kernels ----------------
// conv1 weights per-k masks: w1k[k*4+ci] = u64, bit co = sign(w1[co][ci][k])
__global__ void pack_w1k(const float* __restrict__ w1, u64* __restrict__ dst) {
    int t = blockIdx.x * blockDim.x + threadIdx.x;
    if (t >= 41 * 3) return;
    int ci = t % 3;
    int k = t / 3;
    u64 word = 0;
    for (int co = 0; co < 64; ++co)
        if (w1[(co * 3 + ci) * 41 + k] < 0.f) word |= 1ull << co;
    dst[k * 4 + ci] = word;
}

__global__ void pack_wT(const float* __restrict__ w, u64* __restrict__ wT,
                        int Co, int CIW) {
    int t = blockIdx.x * blockDim.x + threadIdx.x;
    if (t >= Co * 41 * CIW) return;
    int co = t % Co;
    int rem = t / Co;
    int h = rem % CIW;
    int k = rem / CIW;
    int CI = CIW * 64;
    u64 word = 0;
    for (int c = 0; c < 64; ++c)
        if (w[((size_t)co * CI + h * 64 + c) * 41 + k] < 0.f) word |= 1ull << c;
    wT[t] = word;
}

__global__ void pack_fw1T(const float* __restrict__ w, u64* __restrict__ wT) {
    int t = blockIdx.x * blockDim.x + threadIdx.x;
    if (t >= 156 * 1024) return;
    int row = t & 1023;
    int j = t >> 10;
    const float* base = w + (size_t)row * 9984 + j * 64;
    u64 word = 0;
    for (int c = 0; c < 64; ++c)
        if (base[c] < 0.f) word |= 1ull << c;
    wT[t] = word;
}

__global__ void pack_fw2T(const float* __restrict__ w, u64* __restrict__ wT) {
    int t = blockIdx.x * blockDim.x + threadIdx.x;
    if (t >= 16 * 1000) return;
    int row = t % 1000;
    int j = t / 1000;
    const float* base = w + (size_t)row * 1024 + j * 64;
    u64 word = 0;
    for (int c = 0; c < 64; ++c)
        if (base[c] < 0.f) word |= 1ull << c;
    wT[t] = word;
}

__global__ void repack_a5(const u64* __restrict__ a5, u64* __restrict__ a5F) {
    int t = blockIdx.x * blockDim.x + threadIdx.x;
    if (t >= NB * 156) return;
    int j = t % 156;
    int n = t / 156;
    u64 word = 0;
    #pragma unroll
    for (int c = 0; c < 64; ++c) {
        int jj = j * 64 + c;
        int chan = jj / 78;
        int tp = jj - chan * 78;
        u64 src = a5[((size_t)n * C5 + tp) * 2 + (chan >> 6)];
        word |= ((src >> (chan & 63)) & 1ull) << c;
    }
    a5F[t] = word;
}

// ---------------- conv1: y staged in LDS (shared across 64 q), co-tiled regs ----------------
// Float sequence per (q,co,r) identical to R14/R15/R16 (all refcheck'd):
// y = fl(fl(fl(x*sq0)+b0)*0.1f);  A = +-y0; A = fl(A +- y1); A = fl(A +- y2);
// S = fl(S + A) over k ascending;  pre = fl(fl(S*sq1)+b1).
__global__ __launch_bounds__(64) void conv1_s(
        const float* __restrict__ x, const u64* __restrict__ w1k,
        const float* __restrict__ s0, const float* __restrict__ b0,
        const float* __restrict__ s1, const float* __restrict__ b1,
        u64* __restrict__ a1) {
    __shared__ float yl[3][232];
    __shared__ float s1l[64], b1l[64];
    int lane = threadIdx.x;
    int qb = blockIdx.x * 64;
    int n = blockIdx.y;

    // stage y (pure function of x[t] -> shared across q, bit-identical)
    #pragma unroll
    for (int ci = 0; ci < 3; ++ci) {
        float sq = (s0[ci] < 0.f) ? -0.1f : 0.1f;
        float bb = b0[ci];
        const float* xp = x + ((size_t)n * 3 + ci) * L_X;
        for (int i = lane; i < 232; i += 64) {
            int t = 3 * qb + i;
            t = (t < L_X) ? t : (L_X - 1);   // clamp (phantom tail only)
            float xsb = __fadd_rn(__fmul_rn(xp[t], sq), bb);
            yl[ci][i] = __fmul_rn(xsb, 0.1f);
        }
    }
    s1l[lane] = s1[lane];
    b1l[lane] = b1[lane];
    __syncthreads();

    int q = qb + lane;
    bool valid = q < P1;
    int base = 3 * lane;
    u64 word = 0;

    #pragma unroll 1
    for (int tile = 0; tile < 4; ++tile) {
        float S[16][3];
        #pragma unroll
        for (int c = 0; c < 16; ++c)
            #pragma unroll
            for (int r = 0; r < 3; ++r) S[c][r] = 0.f;

        #pragma unroll 1
        for (int k = 0; k < 41; ++k) {
            // 9 LDS reads: taps base+k .. base+k+2 per ci (stride-3 -> conflict-free)
            float y0[3], y1[3], y2[3];
            #pragma unroll
            for (int r = 0; r < 3; ++r) {
                y0[r] = yl[0][base + k + r];
                y1[r] = yl[1][base + k + r];
                y2[r] = yl[2][base + k + r];
            }
            // per-k weight masks (uniform -> SGPR), tile-segment, SALU synthesis
            u32 t0 = (u32)(w1k[k * 4 + 0] >> (tile * 16));
            u32 t1 = (u32)(w1k[k * 4 + 1] >> (tile * 16));
            u32 t2 = (u32)(w1k[k * 4 + 2] >> (tile * 16));
            #pragma unroll
            for (int c = 0; c < 16; ++c) {
                float wf0 = __uint_as_float(0x3F800000u | (((t0 >> c) & 1u) << 31));
                float wf1 = __uint_as_float(0x3F800000u | (((t1 >> c) & 1u) << 31));
                float wf2 = __uint_as_float(0x3F800000u | (((t2 >> c) & 1u) << 31));
                #pragma unroll
                for (int r = 0; r < 3; ++r) {
                    float A = __fmul_rn(y0[r], wf0);      // = +-y0 exactly
                    A = __fmaf_rn(y1[r], wf1, A);         // = fl(A +- y1)
                    A = __fmaf_rn(y2[r], wf2, A);         // = fl(A +- y2)
                    S[c][r] = __fadd_rn(S[c][r], A);
                }
            }
        }
        // epilogue for this co tile
        #pragma unroll
        for (int c = 0; c < 16; ++c) {
            int co = tile * 16 + c;
            float sq1 = (s1l[co] < 0.f) ? -0.1f : 0.1f;
            float bb1 = b1l[co];
            bool neg = true;
            #pragma unroll
            for (int r = 0; r < 3; ++r) {
                float pre = __fadd_rn(__fmul_rn(S[c][r], sq1), bb1);
                neg = neg && (pre < 0.f);
            }
            word |= (u64)(neg ? 1 : 0) << co;
        }
    }
    if (valid) a1[(size_t)n * P1 + q] = word;
}

// ---------------- binary conv: popcount fast path + per-r guarded exact fallback ----------------
template <int CIW, int POOLK>
__global__ void bconv_g(const u64* __restrict__ abits_in, const u64* __restrict__ wT,
                        const float* __restrict__ s, const float* __restrict__ b,
                        u64* __restrict__ abits_out, int Lin, int Lq, double G) {
    constexpr int BITS = 41 * CIW * 64;
    int q = blockIdx.x;
    int n = blockIdx.y;
    int co = threadIdx.x;
    int Co = blockDim.x;
    int wave = co >> 6;
    int CoW = Co >> 6;
    float sqf = (s[co] < 0.f) ? -0.1f : 0.1f;
    float bf  = b[co];
    const u64* wp = wT + co;
    const u64* ap = abits_in + ((size_t)n * Lin + (size_t)POOLK * q) * CIW;

    int pc[POOLK];
    #pragma unroll
    for (int r = 0; r < POOLK; ++r) pc[r] = 0;
    #pragma unroll 1
    for (int k = 0; k < 41; ++k) {
        u64 wk[CIW];
        #pragma unroll
        for (int h = 0; h < CIW; ++h) wk[h] = wp[((size_t)k * CIW + h) * Co];
        const u64* ak = ap + (size_t)(2 * k) * CIW;
        #pragma unroll
        for (int r = 0; r < POOLK; ++r) {
            #pragma unroll
            for (int h = 0; h < CIW; ++h)
                pc[r] += (int)__popcll(ak[r * CIW + h] ^ wk[h]);
        }
    }
    const double vv = (double)0.1f * (double)0.1f;
    double svv = (sqf < 0.f) ? -vv : vv;
    double bd = (double)bf;
    bool negr[POOLK];
    bool flagr[POOLK];
    #pragma unroll
    for (int r = 0; r < POOLK; ++r) {
        double pre = (double)(BITS - 2 * pc[r]) * svv + bd;
        negr[r] = (pre < 0.0);
        flagr[r] = (fabs(pre) < G);
    }
    #pragma unroll
    for (int r = 0; r < POOLK; ++r) {
        if (__ballot(flagr[r]) != 0ull) {
            float S = 0.f;
            #pragma unroll 1
            for (int k = 0; k < 41; ++k) {
                float A = 0.f;
                #pragma unroll
                for (int h = 0; h < CIW; ++h) {
                    u64 u = ap[(size_t)(2 * k + r) * CIW + h]
                          ^ wp[((size_t)k * CIW + h) * Co];
                    chain64(A, u);
                }
                S = __fadd_rn(S, A);
            }
            negr[r] = (__fadd_rn(__fmul_rn(S, sqf), bf) < 0.f);
        }
    }
    bool neg = true;
    #pragma unroll
    for (int r = 0; r < POOLK; ++r) neg = neg && negr[r];
    u64 word = __ballot(neg);
    if ((co & 63) == 0) abits_out[((size_t)n * Lq + q) * CoW + wave] = word;
}

// ---------------- fc1: single sequential chain over 9984 bits ----------------
__global__ __launch_bounds__(64) void fc1_k(
        const u64* __restrict__ a5F, const u64* __restrict__ fw1T,
        const float* __restrict__ s6, const float* __restrict__ b6,
        u64* __restrict__ y6b) {
    int g = blockIdx.x;
    int n = blockIdx.y;
    int lane = threadIdx.x;
    int row = g * 64 + lane;
    float S = 0.f;
    #pragma unroll 1
    for (int j = 0; j < 156; ++j) {
        u64 u = a5F[(size_t)n * 156 + j] ^ fw1T[(size_t)j * 1024 + row];
        chain64(S, u);
    }
    float pre = __fadd_rn(__fmul_rn(S, (s6[row] < 0.f) ? -0.1f : 0.1f), b6[row]);
    u64 word = __ballot(pre < 0.f);
    if (lane == 0) y6b[n * 16 + g] = word;
}

// ---------------- fc2: single chain over 1024 bits -> f32 out ----------------
__global__ void fc2_k(const u64* __restrict__ y6b, const u64* __restrict__ fw2T,
                      const float* __restrict__ s7, const float* __restrict__ b7,
                      float* __restrict__ out) {
    int t = blockIdx.x * blockDim.x + threadIdx.x;
    if (t >= NB * 1000) return;
    int r = t % 1000;
    int n = t / 1000;
    float S = 0.f;
    #pragma unroll 1
    for (int j = 0; j < 16; ++j) {
        u64 u = y6b[n * 16 + j] ^ fw2T[j * 1000 + r];
        chain64(S, u);
    }
    out[t] = __fadd_rn(__fmul_rn(S, (s7[r] < 0.f) ? -0.1f : 0.1f), b7[r]);
}

// ---------------- launch ----------------
extern "C" void kernel_launch(void* const* d_in, const int* in_sizes, int n_in,
                              void* d_out, int out_size, void* d_ws, size_t ws_size,
                              hipStream_t stream) {
    const float* x   = (const float*)d_in[0];
    const float* s0  = (const float*)d_in[1];
    const float* b0  = (const float*)d_in[2];
    const float* w1  = (const float*)d_in[3];
    const float* s1  = (const float*)d_in[4];
    const float* b1  = (const float*)d_in[5];
    const float* w2  = (const float*)d_in[6];
    const float* s2  = (const float*)d_in[7];
    const float* b2  = (const float*)d_in[8];
    const float* w3  = (const float*)d_in[9];
    const float* s3  = (const float*)d_in[10];
    const float* b3  = (const float*)d_in[11];
    const float* w4  = (const float*)d_in[12];
    const float* s4  = (const float*)d_in[13];
    const float* b4  = (const float*)d_in[14];
    const float* w5  = (const float*)d_in[15];
    const float* s5  = (const float*)d_in[16];
    const float* b5  = (const float*)d_in[17];
    const float* fw1 = (const float*)d_in[18];
    const float* s6  = (const float*)d_in[19];
    const float* b6  = (const float*)d_in[20];
    const float* fw2 = (const float*)d_in[21];
    const float* s7  = (const float*)d_in[22];
    const float* b7  = (const float*)d_in[23];

    u64* p = (u64*)d_ws;
    u64* w1kb = p; p += 41 * 4;
    u64* w2T  = p; p += 41 * 64;
    u64* w3T  = p; p += 41 * 128;
    u64* w4T  = p; p += 82 * 128;
    u64* w5T  = p; p += 82 * 128;
    u64* fw1T = p; p += 156 * 1024;
    u64* fw2T = p; p += 16 * 1000;
    u64* a1   = p; p += (size_t)NB * P1;
    u64* a2   = p; p += (size_t)NB * P2;
    u64* a3   = p; p += (size_t)NB * P3 * 2;
    u64* a4   = p; p += (size_t)NB * P4 * 2;
    u64* a5   = p; p += (size_t)NB * C5 * 2;
    u64* a5F  = p; p += (size_t)NB * 156;
    u64* y6b  = p; p += (size_t)NB * 16;

    const double G64  = 2.0e-4;
    const double G128 = 5.0e-4;

    pack_w1k<<<1, 128, 0, stream>>>(w1, w1kb);
    pack_wT<<<(64 * 41 + 255) / 256, 256, 0, stream>>>(w2, w2T, 64, 1);
    pack_wT<<<(128 * 41 + 255) / 256, 256, 0, stream>>>(w3, w3T, 128, 1);
    pack_wT<<<(128 * 82 + 255) / 256, 256, 0, stream>>>(w4, w4T, 128, 2);
    pack_wT<<<(128 * 82 + 255) / 256, 256, 0, stream>>>(w5, w5T, 128, 2);
    pack_fw1T<<<(156 * 1024 + 255) / 256, 256, 0, stream>>>(fw1, fw1T);
    pack_fw2T<<<(16 * 1000 + 255) / 256, 256, 0, stream>>>(fw2, fw2T);

    conv1_s<<<dim3((P1 + 63) / 64, NB), 64, 0, stream>>>(x, w1kb, s0, b0, s1, b1, a1);
    bconv_g<1, 3><<<dim3(P2, NB), 64, 0, stream>>>(a1, w2T, s2, b2, a2, P1, P2, G64);
    bconv_g<1, 3><<<dim3(P3, NB), 128, 0, stream>>>(a2, w3T, s3, b3, a3, P2, P3, G64);
    bconv_g<2, 3><<<dim3(P4, NB), 128, 0, stream>>>(a3, w4T, s4, b4, a4, P3, P4, G128);
    bconv_g<2, 1><<<dim3(C5, NB), 128, 0, stream>>>(a4, w5T, s5, b5, a5, P4, C5, G128);
    repack_a5<<<(NB * 156 + 255) / 256, 256, 0, stream>>>(a5, a5F);
    fc1_k<<<dim3(16, NB), 64, 0, stream>>>(a5F, fw1T, s6, b6, y6b);
    fc2_k<<<(NB * 1000 + 255) / 256, 256, 0, stream>>>(y6b, fw2T, s7, b7, (float*)d_out);
}